// Round 3
// baseline (552.980 us; speedup 1.0000x reference)
//
#include <hip/hip_runtime.h>
#include <hip/hip_bf16.h>

// Problem constants
#define B_   4
#define T_   2048
#define C_   1024
#define H_   16
#define D_   64
#define NQKV 3072
#define M_   (B_*T_)

typedef __attribute__((ext_vector_type(8))) short bf16x8;   // 8 bf16 = 4 VGPR (MFMA A/B frag)
typedef __attribute__((ext_vector_type(4))) float f32x4;    // MFMA C/D frag
typedef __hip_bfloat16 bf16;

#define NEG_BIG (-1e30f)

__device__ inline short f2bs(float f) {
    bf16 h = __float2bfloat16(f);
    return *(short*)&h;
}

__device__ inline bf16x8 cvt_f32x8(const float* __restrict__ p) {
    const float4 a = *(const float4*)p;
    const float4 b = *(const float4*)(p + 4);
    bf16x8 o;
    o[0] = f2bs(a.x); o[1] = f2bs(a.y); o[2] = f2bs(a.z); o[3] = f2bs(a.w);
    o[4] = f2bs(b.x); o[5] = f2bs(b.y); o[6] = f2bs(b.z); o[7] = f2bs(b.w);
    return o;
}

// ---------------- weight transpose (fp32 in -> bf16 out): out[c][r] = in[r][c] ----
__global__ __launch_bounds__(256) void transpose_k(const float* __restrict__ in,
                                                   bf16* __restrict__ out,
                                                   int R, int Ccol) {
    __shared__ short t[32][33];
    const int x = threadIdx.x & 31, y = threadIdx.x >> 5;  // 32 x 8
    const int r0 = blockIdx.y * 32, c0 = blockIdx.x * 32;
#pragma unroll
    for (int i = 0; i < 4; i++)
        t[y + 8*i][x] = f2bs(in[(long)(r0 + y + 8*i) * Ccol + c0 + x]);
    __syncthreads();
#pragma unroll
    for (int i = 0; i < 4; i++)
        ((short*)out)[(long)(c0 + y + 8*i) * R + r0 + x] = t[x][y + 8*i];
}

// ---------------- GEMM: C[M,N] = A[M,K] * Bt[N,K]^T  (m93-style staging) ----------
// MODE 0: A is fp32 (x), epilogue scatters bf16 to k/q/v buffers (split order k,q,v!)
// MODE 1: A is bf16 (att), epilogue stores fp32 to outp[M,N]
template<int MODE>
__global__ __launch_bounds__(256) void gemm_bt(const void* __restrict__ Av,
                                               const bf16* __restrict__ Bt,
                                               float* __restrict__ outp,
                                               bf16* __restrict__ qb,
                                               bf16* __restrict__ kb,
                                               bf16* __restrict__ vb,
                                               int K, int N) {
    __shared__ __align__(16) short As[128 * 32];
    __shared__ __align__(16) short Bs[128 * 32];
    const int tid  = threadIdx.x;
    const int w    = tid >> 6, lane = tid & 63;
    const int g    = lane >> 4, ln = lane & 15;
    const int m0   = blockIdx.y * 128, n0 = blockIdx.x * 128;
    const int wm   = w & 1, wn = w >> 1;          // wave quadrant (2x2 of 64x64)
    const int srow = tid >> 2;                    // 0..63  (staging row)
    const int scol = (tid & 3) * 8;               // 0/8/16/24 (staging k-col)

    const float* Af = (const float*)Av;           // MODE 0
    const bf16*  Ab = (const bf16*)Av;            // MODE 1

    f32x4 acc[4][4] = {};

    for (int k0 = 0; k0 < K; k0 += 32) {
        // global -> registers
        bf16x8 a0, a1;
        if (MODE == 0) {
            a0 = cvt_f32x8(Af + (long)(m0 +      srow) * K + k0 + scol);
            a1 = cvt_f32x8(Af + (long)(m0 + 64 + srow) * K + k0 + scol);
        } else {
            a0 = *(const bf16x8*)&Ab[(long)(m0 +      srow) * K + k0 + scol];
            a1 = *(const bf16x8*)&Ab[(long)(m0 + 64 + srow) * K + k0 + scol];
        }
        const bf16x8 b0 = *(const bf16x8*)&Bt[(long)(n0 +      srow) * K + k0 + scol];
        const bf16x8 b1 = *(const bf16x8*)&Bt[(long)(n0 + 64 + srow) * K + k0 + scol];
        __syncthreads();   // previous iteration's fragment reads complete
        *(bf16x8*)&As[      srow  * 32 + scol] = a0;
        *(bf16x8*)&As[(64 + srow) * 32 + scol] = a1;
        *(bf16x8*)&Bs[      srow  * 32 + scol] = b0;
        *(bf16x8*)&Bs[(64 + srow) * 32 + scol] = b1;
        __syncthreads();   // staging visible to all waves

        bf16x8 af[4], bfr[4];
#pragma unroll
        for (int i = 0; i < 4; i++)
            af[i]  = *(const bf16x8*)&As[(wm * 64 + i * 16 + ln) * 32 + g * 8];
#pragma unroll
        for (int j = 0; j < 4; j++)
            bfr[j] = *(const bf16x8*)&Bs[(wn * 64 + j * 16 + ln) * 32 + g * 8];
#pragma unroll
        for (int i = 0; i < 4; i++)
#pragma unroll
            for (int j = 0; j < 4; j++)
                acc[i][j] = __builtin_amdgcn_mfma_f32_16x16x32_bf16(af[i], bfr[j], acc[i][j], 0, 0, 0);
    }

#pragma unroll
    for (int i = 0; i < 4; i++) {
#pragma unroll
        for (int j = 0; j < 4; j++) {
#pragma unroll
            for (int r = 0; r < 4; r++) {
                const int row = m0 + wm * 64 + i * 16 + g * 4 + r;   // C/D: row = quad*4+reg
                const int col = n0 + wn * 64 + j * 16 + ln;          // C/D: col = lane&15
                if (MODE == 1) {
                    outp[(long)row * N + col] = acc[i][j][r];        // fp32 output
                } else {
                    const bf16 val = __float2bfloat16(acc[i][j][r]);
                    const int b = row >> 11, t = row & (T_ - 1);
                    const int seg = col >> 10;                 // 0:K 1:Q 2:V (split order!)
                    const int c = col & (C_ - 1), h = c >> 6, d = c & 63;
                    if (seg == 0)
                        kb[(((long)(b * H_ + h)) * T_ + t) * D_ + d] = val;
                    else if (seg == 1)
                        qb[(((long)(b * H_ + h)) * T_ + t) * D_ + d] = val;
                    else  // V stored transposed [B,H,D,T] for flash B-operand reads
                        vb[(((long)(b * H_ + h)) * D_ + d) * T_ + t] = val;
                }
            }
        }
    }
}

// ---------------- flash attention (causal, online softmax) ----------------
// grid: (T/64, B*H). Block 256 = 4 waves; wave w handles q-rows q0+16w .. +15.
__global__ __launch_bounds__(256) void flash(const bf16* __restrict__ qb,
                                             const bf16* __restrict__ kb,
                                             const bf16* __restrict__ vb,
                                             bf16* __restrict__ att) {
    __shared__ __align__(16) bf16 Ks[32 * 64];       // [key][d]
    __shared__ __align__(16) bf16 Vs[64 * 32];       // [d][key] (vb already transposed)
    __shared__ __align__(16) bf16 Ps[4 * 16 * 32];   // per-wave P round-trip buffer
    const int tid = threadIdx.x, w = tid >> 6, lane = tid & 63;
    const int g = lane >> 4, ln = lane & 15;
    const int bh = blockIdx.y, q0 = blockIdx.x * 64;
    const int b = bh >> 4, h = bh & 15;

    // Q fragments (A-layout): lane holds Q[q0+16w+ln][g*8+j (+32)]
    const bf16* qptr = qb + ((long)bh * T_ + q0 + w * 16 + ln) * D_;
    const bf16x8 qf0 = *(const bf16x8*)(qptr + g * 8);
    const bf16x8 qf1 = *(const bf16x8*)(qptr + 32 + g * 8);

    f32x4 o[4] = {};
    float m[4], l[4];
#pragma unroll
    for (int r = 0; r < 4; r++) { m[r] = NEG_BIG; l[r] = 0.f; }
    bf16* myP = &Ps[w * 16 * 32];
    const int row_base = q0 + w * 16 + g * 4;
    const int nkt = (q0 + 64) >> 5;          // causal: only keys <= q0+63

    for (int it = 0; it < nkt; ++it) {
        const int k0 = it * 32;
        // global -> registers: K tile (32x64) and V tile (64x32, [d][key])
        const bf16x8 kv = *(const bf16x8*)&kb[((long)bh * T_ + k0) * D_ + tid * 8];
        const bf16x8 vv = *(const bf16x8*)&vb[((long)bh * D_ + (tid >> 2)) * T_ + k0 + (tid & 3) * 8];
        __syncthreads();                      // all waves done with previous K/V tiles
        *(bf16x8*)&Ks[tid * 8] = kv;
        *(bf16x8*)&Vs[tid * 8] = vv;          // (d=tid>>2, key=(tid&3)*8+j) -> d*32+key = 8*tid
        __syncthreads();

        // S = Q K^T (fp32, C-layout): two 16-key blocks, d contracted in 2 chunks
        f32x4 s0 = {}, s1 = {};
        bf16x8 kf;
        kf = *(const bf16x8*)&Ks[ln * 64 + g * 8];
        s0 = __builtin_amdgcn_mfma_f32_16x16x32_bf16(qf0, kf, s0, 0, 0, 0);
        kf = *(const bf16x8*)&Ks[ln * 64 + 32 + g * 8];
        s0 = __builtin_amdgcn_mfma_f32_16x16x32_bf16(qf1, kf, s0, 0, 0, 0);
        kf = *(const bf16x8*)&Ks[(16 + ln) * 64 + g * 8];
        s1 = __builtin_amdgcn_mfma_f32_16x16x32_bf16(qf0, kf, s1, 0, 0, 0);
        kf = *(const bf16x8*)&Ks[(16 + ln) * 64 + 32 + g * 8];
        s1 = __builtin_amdgcn_mfma_f32_16x16x32_bf16(qf1, kf, s1, 0, 0, 0);

        // online softmax per row (rows g*4+r; 16 lanes per row share via shfl_xor)
#pragma unroll
        for (int r = 0; r < 4; r++) {
            const int rowg = row_base + r;
            float v0 = (k0 + ln      <= rowg) ? s0[r] * 0.03125f : NEG_BIG;  // scale = C^-0.5 = 1/32
            float v1 = (k0 + 16 + ln <= rowg) ? s1[r] * 0.03125f : NEG_BIG;
            float mt = fmaxf(v0, v1);
#pragma unroll
            for (int off = 1; off < 16; off <<= 1) mt = fmaxf(mt, __shfl_xor(mt, off, 64));
            const float mn = fmaxf(m[r], mt);
            const float al = __expf(m[r] - mn);
            const float p0 = __expf(v0 - mn), p1 = __expf(v1 - mn);
            float rs = p0 + p1;
#pragma unroll
            for (int off = 1; off < 16; off <<= 1) rs += __shfl_xor(rs, off, 64);
            l[r] = l[r] * al + rs;
            m[r] = mn;
            o[0][r] *= al; o[1][r] *= al; o[2][r] *= al; o[3][r] *= al;
            // P: C-layout -> LDS (bf16) for A-layout reload
            myP[(g * 4 + r) * 32 + ln]      = __float2bfloat16(p0);
            myP[(g * 4 + r) * 32 + 16 + ln] = __float2bfloat16(p1);
        }
        __syncthreads();                      // P writes visible (conservative)
        const bf16x8 pf = *(const bf16x8*)&myP[ln * 32 + g * 8];
#pragma unroll
        for (int nb = 0; nb < 4; nb++) {
            const bf16x8 vf = *(const bf16x8*)&Vs[(nb * 16 + ln) * 32 + g * 8];
            o[nb] = __builtin_amdgcn_mfma_f32_16x16x32_bf16(pf, vf, o[nb], 0, 0, 0);
        }
    }

    float inv[4];
#pragma unroll
    for (int r = 0; r < 4; r++) inv[r] = 1.f / l[r];
#pragma unroll
    for (int nb = 0; nb < 4; nb++)
#pragma unroll
        for (int r = 0; r < 4; r++) {
            const int t = row_base + r;
            att[((long)b * T_ + t) * C_ + h * D_ + nb * 16 + ln] =
                __float2bfloat16(o[nb][r] * inv[r]);
        }
}

// ---------------- launch ----------------
extern "C" void kernel_launch(void* const* d_in, const int* in_sizes, int n_in,
                              void* d_out, int out_size, void* d_ws, size_t ws_size,
                              hipStream_t stream) {
    const float* x     = (const float*)d_in[0];   // [B,T,C] fp32
    const float* Wqkv  = (const float*)d_in[1];   // [C,3C]  fp32
    const float* Wproj = (const float*)d_in[2];   // [C,C]   fp32
    float* out = (float*)d_out;                   // [B,T,C] fp32

    char* ws = (char*)d_ws;
    bf16* wqkv_t  = (bf16*)(ws);                 // [3072,1024] bf16  6291456 B
    bf16* wproj_t = (bf16*)(ws + 6291456);       // [1024,1024] bf16  2097152 B
    bf16* qb      = (bf16*)(ws + 8388608);       // [B,H,T,D]   bf16 16777216 B
    bf16* kb      = (bf16*)(ws + 25165824);      // [B,H,T,D]   bf16 16777216 B
    bf16* vb      = (bf16*)(ws + 41943040);      // [B,H,D,T]   bf16 16777216 B
    bf16* att     = (bf16*)(ws + 58720256);      // [B,T,C]     bf16 16777216 B (end 75497472)
    (void)ws_size; (void)in_sizes; (void)n_in; (void)out_size;

    transpose_k<<<dim3(NQKV / 32, C_ / 32), dim3(256), 0, stream>>>(Wqkv, wqkv_t, C_, NQKV);
    transpose_k<<<dim3(C_ / 32, C_ / 32), dim3(256), 0, stream>>>(Wproj, wproj_t, C_, C_);
    gemm_bt<0><<<dim3(NQKV / 128, M_ / 128), dim3(256), 0, stream>>>(
        (const void*)x, wqkv_t, (float*)nullptr, qb, kb, vb, C_, NQKV);
    flash<<<dim3(T_ / 64, B_ * H_), dim3(256), 0, stream>>>(qb, kb, vb, att);
    gemm_bt<1><<<dim3(C_ / 128, M_ / 128), dim3(256), 0, stream>>>(
        (const void*)att, wproj_t, out, (bf16*)nullptr, (bf16*)nullptr, (bf16*)nullptr, C_, C_);
}

// Round 4
// 353.418 us; speedup vs baseline: 1.5647x; 1.5647x over previous
//
#include <hip/hip_runtime.h>
#include <hip/hip_bf16.h>

// Problem constants
#define B_   4
#define T_   2048
#define C_   1024
#define H_   16
#define D_   64
#define NQKV 3072
#define M_   (B_*T_)

typedef __attribute__((ext_vector_type(8))) short bf16x8;   // 8 bf16 = 4 VGPR (MFMA A/B frag)
typedef __attribute__((ext_vector_type(4))) short bf16x4;   // 8B packed store
typedef __attribute__((ext_vector_type(4))) float f32x4;    // MFMA C/D frag
typedef __hip_bfloat16 bf16;

__device__ inline short f2bs(float f) {
    bf16 h = __float2bfloat16(f);
    return *(short*)&h;
}

__device__ inline bf16x8 cvt_f32x8(const float* __restrict__ p) {
    const float4 a = *(const float4*)p;
    const float4 b = *(const float4*)(p + 4);
    bf16x8 o;
    o[0] = f2bs(a.x); o[1] = f2bs(a.y); o[2] = f2bs(a.z); o[3] = f2bs(a.w);
    o[4] = f2bs(b.x); o[5] = f2bs(b.y); o[6] = f2bs(b.z); o[7] = f2bs(b.w);
    return o;
}

// ---------------- weight transpose (fp32 in -> bf16 out): out[c][r] = in[r][c] ----
__global__ __launch_bounds__(256) void transpose_k(const float* __restrict__ in,
                                                   bf16* __restrict__ out,
                                                   int R, int Ccol) {
    __shared__ short t[32][33];
    const int x = threadIdx.x & 31, y = threadIdx.x >> 5;  // 32 x 8
    const int r0 = blockIdx.y * 32, c0 = blockIdx.x * 32;
#pragma unroll
    for (int i = 0; i < 4; i++)
        t[y + 8*i][x] = f2bs(in[(long)(r0 + y + 8*i) * Ccol + c0 + x]);
    __syncthreads();
#pragma unroll
    for (int i = 0; i < 4; i++)
        ((short*)out)[(long)(c0 + y + 8*i) * R + r0 + x] = t[x][y + 8*i];
}

// ---------------- GEMM: C[M,N] = A[M,K] * Bt[N,K]^T  (unchanged from round 3) ----
template<int MODE>
__global__ __launch_bounds__(256) void gemm_bt(const void* __restrict__ Av,
                                               const bf16* __restrict__ Bt,
                                               float* __restrict__ outp,
                                               bf16* __restrict__ qb,
                                               bf16* __restrict__ kb,
                                               bf16* __restrict__ vb,
                                               int K, int N) {
    __shared__ __align__(16) short As[128 * 32];
    __shared__ __align__(16) short Bs[128 * 32];
    const int tid  = threadIdx.x;
    const int w    = tid >> 6, lane = tid & 63;
    const int g    = lane >> 4, ln = lane & 15;
    const int m0   = blockIdx.y * 128, n0 = blockIdx.x * 128;
    const int wm   = w & 1, wn = w >> 1;
    const int srow = tid >> 2;
    const int scol = (tid & 3) * 8;

    const float* Af = (const float*)Av;           // MODE 0
    const bf16*  Ab = (const bf16*)Av;            // MODE 1

    f32x4 acc[4][4] = {};

    for (int k0 = 0; k0 < K; k0 += 32) {
        bf16x8 a0, a1;
        if (MODE == 0) {
            a0 = cvt_f32x8(Af + (long)(m0 +      srow) * K + k0 + scol);
            a1 = cvt_f32x8(Af + (long)(m0 + 64 + srow) * K + k0 + scol);
        } else {
            a0 = *(const bf16x8*)&Ab[(long)(m0 +      srow) * K + k0 + scol];
            a1 = *(const bf16x8*)&Ab[(long)(m0 + 64 + srow) * K + k0 + scol];
        }
        const bf16x8 b0 = *(const bf16x8*)&Bt[(long)(n0 +      srow) * K + k0 + scol];
        const bf16x8 b1 = *(const bf16x8*)&Bt[(long)(n0 + 64 + srow) * K + k0 + scol];
        __syncthreads();
        *(bf16x8*)&As[      srow  * 32 + scol] = a0;
        *(bf16x8*)&As[(64 + srow) * 32 + scol] = a1;
        *(bf16x8*)&Bs[      srow  * 32 + scol] = b0;
        *(bf16x8*)&Bs[(64 + srow) * 32 + scol] = b1;
        __syncthreads();

        bf16x8 af[4], bfr[4];
#pragma unroll
        for (int i = 0; i < 4; i++)
            af[i]  = *(const bf16x8*)&As[(wm * 64 + i * 16 + ln) * 32 + g * 8];
#pragma unroll
        for (int j = 0; j < 4; j++)
            bfr[j] = *(const bf16x8*)&Bs[(wn * 64 + j * 16 + ln) * 32 + g * 8];
#pragma unroll
        for (int i = 0; i < 4; i++)
#pragma unroll
            for (int j = 0; j < 4; j++)
                acc[i][j] = __builtin_amdgcn_mfma_f32_16x16x32_bf16(af[i], bfr[j], acc[i][j], 0, 0, 0);
    }

#pragma unroll
    for (int i = 0; i < 4; i++) {
#pragma unroll
        for (int j = 0; j < 4; j++) {
#pragma unroll
            for (int r = 0; r < 4; r++) {
                const int row = m0 + wm * 64 + i * 16 + g * 4 + r;
                const int col = n0 + wn * 64 + j * 16 + ln;
                if (MODE == 1) {
                    outp[(long)row * N + col] = acc[i][j][r];
                } else {
                    const bf16 val = __float2bfloat16(acc[i][j][r]);
                    const int b = row >> 11, t = row & (T_ - 1);
                    const int seg = col >> 10;                 // 0:K 1:Q 2:V
                    const int c = col & (C_ - 1), h = c >> 6, d = c & 63;
                    if (seg == 0)
                        kb[(((long)(b * H_ + h)) * T_ + t) * D_ + d] = val;
                    else if (seg == 1)
                        qb[(((long)(b * H_ + h)) * T_ + t) * D_ + d] = val;
                    else
                        vb[(((long)(b * H_ + h)) * D_ + d) * T_ + t] = val;
                }
            }
        }
    }
}

// ---------------- flash v2: no-max softmax, swapped PV, swizzled LDS ----------------
// grid: (T/128, B*H). Block 256 = 4 waves. Wave w: q rows {q0+qi*64+w*16+0..15}, qi=0,1.
// LDS rows are 64 elem (128B = 8 x 16B chunks); chunk swizzle c8' = c8 ^ (row&7).
__global__ __launch_bounds__(256) void flash(const bf16* __restrict__ qb,
                                             const bf16* __restrict__ kb,
                                             const bf16* __restrict__ vb,
                                             bf16* __restrict__ att) {
    __shared__ __align__(16) short Ks[64 * 64];      // [key][d]   swizzled
    __shared__ __align__(16) short Vs[64 * 64];      // [d][key]   swizzled
    __shared__ __align__(16) short Ps[4 * 16 * 64];  // per-wave [qrow][key] swizzled
    const int tid = threadIdx.x, w = tid >> 6, lane = tid & 63;
    const int g = lane >> 4, ln = lane & 15;
    const int bh = blockIdx.y, q0 = blockIdx.x * 128;
    const int b = bh >> 4, h = bh & 15;

    // Q fragments (A-layout): qf[qi][chunk], lane = Q[q0+qi*64+w*16+ln][chunk*32+g*8+j]
    bf16x8 qf[2][2];
#pragma unroll
    for (int qi = 0; qi < 2; qi++) {
        const bf16* qp = qb + ((long)bh * T_ + q0 + qi * 64 + w * 16 + ln) * D_;
        qf[qi][0] = *(const bf16x8*)(qp + g * 8);
        qf[qi][1] = *(const bf16x8*)(qp + 32 + g * 8);
    }

    bf16x8 ones;
#pragma unroll
    for (int i = 0; i < 8; i++) ones[i] = 0x3F80;    // bf16 1.0

    f32x4 o[2][4] = {};
    f32x4 l[2] = {};
    short* myP = &Ps[w * 16 * 64];

    // staging chunk ids
    const int c0 = tid, c1 = tid + 256;
    const int k_key0 = c0 >> 3, k_c80 = c0 & 7;
    const int k_key1 = c1 >> 3, k_c81 = c1 & 7;

    const int kend = q0 + 128;
    for (int k0 = 0; k0 < kend; k0 += 64) {
        // global -> regs
        const bf16x8 kr0 = *(const bf16x8*)&kb[((long)bh * T_ + k0 + k_key0) * D_ + k_c80 * 8];
        const bf16x8 kr1 = *(const bf16x8*)&kb[((long)bh * T_ + k0 + k_key1) * D_ + k_c81 * 8];
        const bf16x8 vr0 = *(const bf16x8*)&vb[((long)bh * D_ + k_key0) * T_ + k0 + k_c80 * 8];
        const bf16x8 vr1 = *(const bf16x8*)&vb[((long)bh * D_ + k_key1) * T_ + k0 + k_c81 * 8];
        __syncthreads();   // previous tile's Ks/Vs reads done
        *(bf16x8*)&Ks[k_key0 * 64 + (k_c80 ^ (k_key0 & 7)) * 8] = kr0;
        *(bf16x8*)&Ks[k_key1 * 64 + (k_c81 ^ (k_key1 & 7)) * 8] = kr1;
        *(bf16x8*)&Vs[k_key0 * 64 + (k_c80 ^ (k_key0 & 7)) * 8] = vr0;
        *(bf16x8*)&Vs[k_key1 * 64 + (k_c81 ^ (k_key1 & 7)) * 8] = vr1;
        __syncthreads();   // staging visible

#pragma unroll
        for (int qi = 0; qi < 2; qi++) {
            if (k0 > q0 + qi * 64 + 63) continue;   // tile fully masked for these rows (uniform)

            // ---- S = Q K^T : C-layout row=q local g*4+r, col=key kj*16+ln ----
            f32x4 s[4] = {};
#pragma unroll
            for (int kj = 0; kj < 4; kj++) {
                const int krow = kj * 16 + ln;
                const bf16x8 kf0 = *(const bf16x8*)&Ks[krow * 64 + ((0 + g) ^ (krow & 7)) * 8];
                s[kj] = __builtin_amdgcn_mfma_f32_16x16x32_bf16(qf[qi][0], kf0, s[kj], 0, 0, 0);
                const bf16x8 kf1 = *(const bf16x8*)&Ks[krow * 64 + ((4 + g) ^ (krow & 7)) * 8];
                s[kj] = __builtin_amdgcn_mfma_f32_16x16x32_bf16(qf[qi][1], kf1, s[kj], 0, 0, 0);
            }

            // ---- P = exp(S/32) with causal mask (no running max: |S/32| < ~1) ----
            const int rowg = q0 + qi * 64 + w * 16 + g * 4;   // + r
#pragma unroll
            for (int kj = 0; kj < 4; kj++) {
                const int key = k0 + kj * 16 + ln;
#pragma unroll
                for (int r = 0; r < 4; r++) {
                    float p = __expf(s[kj][r] * 0.03125f);    // scale = C^-0.5 = 1/32
                    p = (key <= rowg + r) ? p : 0.f;
                    const int prow = g * 4 + r;
                    const int pc8 = (kj * 2 + (ln >> 3)) ^ (prow & 7);
                    myP[prow * 64 + pc8 * 8 + (ln & 7)] = f2bs(p);
                }
            }
            asm volatile("s_waitcnt lgkmcnt(0)" ::: "memory");  // wave-local P RAW

            // ---- P frags as B-operand: B[k=key][n=q=ln] = P[ln][key] ----
            const bf16x8 pf0 = *(const bf16x8*)&myP[ln * 64 + ((0 + g) ^ (ln & 7)) * 8];
            const bf16x8 pf1 = *(const bf16x8*)&myP[ln * 64 + ((4 + g) ^ (ln & 7)) * 8];

            // l += ones * P  (C-layout col=q=ln, all rows identical)
            l[qi] = __builtin_amdgcn_mfma_f32_16x16x32_bf16(ones, pf0, l[qi], 0, 0, 0);
            l[qi] = __builtin_amdgcn_mfma_f32_16x16x32_bf16(ones, pf1, l[qi], 0, 0, 0);

            // ---- O^T += V^T P^T : A = V^T frag from Vs[d][key], B = pf ----
#pragma unroll
            for (int nb = 0; nb < 4; nb++) {
                const int drow = nb * 16 + ln;
                const bf16x8 vf0 = *(const bf16x8*)&Vs[drow * 64 + ((0 + g) ^ (drow & 7)) * 8];
                o[qi][nb] = __builtin_amdgcn_mfma_f32_16x16x32_bf16(vf0, pf0, o[qi][nb], 0, 0, 0);
                const bf16x8 vf1 = *(const bf16x8*)&Vs[drow * 64 + ((4 + g) ^ (drow & 7)) * 8];
                o[qi][nb] = __builtin_amdgcn_mfma_f32_16x16x32_bf16(vf1, pf1, o[qi][nb], 0, 0, 0);
            }
        }
    }

    // ---- epilogue: O^T C-layout row=d local (g*4+r), col=q=ln; divide by l, store 8B ----
#pragma unroll
    for (int qi = 0; qi < 2; qi++) {
        const float invl = 1.f / l[qi][0];
        const int q = q0 + qi * 64 + w * 16 + ln;
#pragma unroll
        for (int nb = 0; nb < 4; nb++) {
            bf16x4 pk;
#pragma unroll
            for (int r = 0; r < 4; r++) pk[r] = f2bs(o[qi][nb][r] * invl);
            *(bf16x4*)&att[((long)b * T_ + q) * C_ + h * D_ + nb * 16 + g * 4] = pk;
        }
    }
}

// ---------------- launch ----------------
extern "C" void kernel_launch(void* const* d_in, const int* in_sizes, int n_in,
                              void* d_out, int out_size, void* d_ws, size_t ws_size,
                              hipStream_t stream) {
    const float* x     = (const float*)d_in[0];   // [B,T,C] fp32
    const float* Wqkv  = (const float*)d_in[1];   // [C,3C]  fp32
    const float* Wproj = (const float*)d_in[2];   // [C,C]   fp32
    float* out = (float*)d_out;                   // [B,T,C] fp32

    char* ws = (char*)d_ws;
    bf16* wqkv_t  = (bf16*)(ws);                 // [3072,1024] bf16  6291456 B
    bf16* wproj_t = (bf16*)(ws + 6291456);       // [1024,1024] bf16  2097152 B
    bf16* qb      = (bf16*)(ws + 8388608);       // [B,H,T,D]   bf16 16777216 B
    bf16* kb      = (bf16*)(ws + 25165824);      // [B,H,T,D]   bf16 16777216 B
    bf16* vb      = (bf16*)(ws + 41943040);      // [B,H,D,T]   bf16 16777216 B
    bf16* att     = (bf16*)(ws + 58720256);      // [B,T,C]     bf16 16777216 B (end 75497472)
    (void)ws_size; (void)in_sizes; (void)n_in; (void)out_size;

    transpose_k<<<dim3(NQKV / 32, C_ / 32), dim3(256), 0, stream>>>(Wqkv, wqkv_t, C_, NQKV);
    transpose_k<<<dim3(C_ / 32, C_ / 32), dim3(256), 0, stream>>>(Wproj, wproj_t, C_, C_);
    gemm_bt<0><<<dim3(NQKV / 128, M_ / 128), dim3(256), 0, stream>>>(
        (const void*)x, wqkv_t, (float*)nullptr, qb, kb, vb, C_, NQKV);
    flash<<<dim3(T_ / 128, B_ * H_), dim3(256), 0, stream>>>(qb, kb, vb, att);
    gemm_bt<1><<<dim3(C_ / 128, M_ / 128), dim3(256), 0, stream>>>(
        (const void*)att, wproj_t, out, (bf16*)nullptr, (bf16*)nullptr, (bf16*)nullptr, C_, C_);
}

// Round 5
// 341.515 us; speedup vs baseline: 1.6192x; 1.0349x over previous
//
#include <hip/hip_runtime.h>
#include <hip/hip_bf16.h>

// Problem constants
#define B_   4
#define T_   2048
#define C_   1024
#define H_   16
#define D_   64
#define NQKV 3072
#define M_   (B_*T_)

typedef __attribute__((ext_vector_type(8))) short bf16x8;   // 8 bf16 = 4 VGPR (MFMA A/B frag)
typedef __attribute__((ext_vector_type(4))) short bf16x4;   // 8B packed store
typedef __attribute__((ext_vector_type(4))) float f32x4;    // MFMA C/D frag
typedef __hip_bfloat16 bf16;

__device__ inline short f2bs(float f) {
    bf16 h = __float2bfloat16(f);
    return *(short*)&h;
}

// async global->LDS, 16B per lane. LDS dest must be wave-uniform base + lane*16.
__device__ inline void async_ld16(const bf16* g, bf16* l) {
    __builtin_amdgcn_global_load_lds(
        (const __attribute__((address_space(1))) void*)g,
        (__attribute__((address_space(3))) void*)l, 16, 0, 0);
}

// ---------------- x fp32 -> bf16 (8 elem/thread) ----------------
__global__ __launch_bounds__(256) void cvt_x(const float* __restrict__ in,
                                             bf16* __restrict__ out) {
    const long i = ((long)blockIdx.x * 256 + threadIdx.x) * 8;
    const float4 a = *(const float4*)(in + i);
    const float4 b = *(const float4*)(in + i + 4);
    bf16x8 o;
    o[0] = f2bs(a.x); o[1] = f2bs(a.y); o[2] = f2bs(a.z); o[3] = f2bs(a.w);
    o[4] = f2bs(b.x); o[5] = f2bs(b.y); o[6] = f2bs(b.z); o[7] = f2bs(b.w);
    *(bf16x8*)(out + i) = o;
}

// ---------------- weight transpose (fp32 in -> bf16 out): out[c][r] = in[r][c] ----
__global__ __launch_bounds__(256) void transpose_k(const float* __restrict__ in,
                                                   bf16* __restrict__ out,
                                                   int R, int Ccol) {
    __shared__ short t[32][33];
    const int x = threadIdx.x & 31, y = threadIdx.x >> 5;  // 32 x 8
    const int r0 = blockIdx.y * 32, c0 = blockIdx.x * 32;
#pragma unroll
    for (int i = 0; i < 4; i++)
        t[y + 8*i][x] = f2bs(in[(long)(r0 + y + 8*i) * Ccol + c0 + x]);
    __syncthreads();
#pragma unroll
    for (int i = 0; i < 4; i++)
        ((short*)out)[(long)(c0 + y + 8*i) * R + r0 + x] = t[x][y + 8*i];
}

// ---------------- GEMM: C[M,N] = A[M,K] * Bt[N,K]^T  (m97: global_load_lds) -------
// MODE 0: epilogue scatters bf16 to k/q/v buffers (split order k,q,v!)
// MODE 1: epilogue stores fp32 to outp[M,N]
template<int MODE>
__global__ __launch_bounds__(256) void gemm_bt(const bf16* __restrict__ A,
                                               const bf16* __restrict__ Bt,
                                               float* __restrict__ outp,
                                               bf16* __restrict__ qb,
                                               bf16* __restrict__ kb,
                                               bf16* __restrict__ vb,
                                               int K, int N) {
    __shared__ __align__(16) bf16 As[128 * 32];
    __shared__ __align__(16) bf16 Bs[128 * 32];
    const int tid  = threadIdx.x;
    const int w    = tid >> 6, lane = tid & 63;
    const int g    = lane >> 4, ln = lane & 15;
    const int m0   = blockIdx.y * 128, n0 = blockIdx.x * 128;
    const int wm   = w & 1, wn = w >> 1;           // wave quadrant (2x2 of 64x64)
    const int srow = lane >> 2;                    // 0..15 (16 rows per wave-issue)
    const int scol = (lane & 3) * 8;               // 0/8/16/24

    f32x4 acc[4][4] = {};

    for (int k0 = 0; k0 < K; k0 += 32) {
#pragma unroll
        for (int i = 0; i < 2; i++) {
            const int r = w * 32 + i * 16 + srow;
            // LDS byte offset = 64*(w*32+i*16) + 16*lane  (wave-uniform + lane*16)
            async_ld16(A  + (long)(m0 + r) * K + k0 + scol, &As[r * 32 + scol]);
            async_ld16(Bt + (long)(n0 + r) * K + k0 + scol, &Bs[r * 32 + scol]);
        }
        __syncthreads();   // drains vmcnt -> staging complete & visible

        bf16x8 af[4], bfr[4];
#pragma unroll
        for (int i = 0; i < 4; i++)
            af[i]  = *(const bf16x8*)&As[(wm * 64 + i * 16 + ln) * 32 + g * 8];
#pragma unroll
        for (int j = 0; j < 4; j++)
            bfr[j] = *(const bf16x8*)&Bs[(wn * 64 + j * 16 + ln) * 32 + g * 8];
#pragma unroll
        for (int i = 0; i < 4; i++)
#pragma unroll
            for (int j = 0; j < 4; j++)
                acc[i][j] = __builtin_amdgcn_mfma_f32_16x16x32_bf16(af[i], bfr[j], acc[i][j], 0, 0, 0);
        __syncthreads();   // fragment reads done before next tile's DMA overwrites
    }

#pragma unroll
    for (int i = 0; i < 4; i++) {
#pragma unroll
        for (int j = 0; j < 4; j++) {
#pragma unroll
            for (int r = 0; r < 4; r++) {
                const int row = m0 + wm * 64 + i * 16 + g * 4 + r;   // C/D: row = quad*4+reg
                const int col = n0 + wn * 64 + j * 16 + ln;          // C/D: col = lane&15
                if (MODE == 1) {
                    outp[(long)row * N + col] = acc[i][j][r];        // fp32 output
                } else {
                    const bf16 val = __float2bfloat16(acc[i][j][r]);
                    const int b = row >> 11, t = row & (T_ - 1);
                    const int seg = col >> 10;                 // 0:K 1:Q 2:V (split order!)
                    const int c = col & (C_ - 1), h = c >> 6, d = c & 63;
                    if (seg == 0)
                        kb[(((long)(b * H_ + h)) * T_ + t) * D_ + d] = val;
                    else if (seg == 1)
                        qb[(((long)(b * H_ + h)) * T_ + t) * D_ + d] = val;
                    else  // V stored transposed [B,H,D,T] for flash B-operand reads
                        vb[(((long)(b * H_ + h)) * D_ + d) * T_ + t] = val;
                }
            }
        }
    }
}

// ---------------- flash v2.1: no-max softmax, swapped PV, swizzled LDS,
//                  pair-balanced q-block mapping ----------------
// grid: (T/128, B*H). Block 256 = 4 waves. Wave w: q rows {q0+qi*64+w*16+0..15}.
__global__ __launch_bounds__(256) void flash(const bf16* __restrict__ qb,
                                             const bf16* __restrict__ kb,
                                             const bf16* __restrict__ vb,
                                             bf16* __restrict__ att) {
    __shared__ __align__(16) short Ks[64 * 64];      // [key][d]   swizzled
    __shared__ __align__(16) short Vs[64 * 64];      // [d][key]   swizzled
    __shared__ __align__(16) short Ps[4 * 16 * 64];  // per-wave [qrow][key] swizzled
    const int tid = threadIdx.x, w = tid >> 6, lane = tid & 63;
    const int g = lane >> 4, ln = lane & 15;
    const int bh = blockIdx.y;
    // balanced mapping: consecutive pairs {0,15},{1,14},... sum to equal work
    const int si = blockIdx.x, nqb = T_ / 128;
    const int qblk = (si & 1) ? (nqb - 1 - (si >> 1)) : (si >> 1);
    const int q0 = qblk * 128;
    const int b = bh >> 4, h = bh & 15;

    // Q fragments (A-layout): qf[qi][chunk], lane = Q[q0+qi*64+w*16+ln][chunk*32+g*8+j]
    bf16x8 qf[2][2];
#pragma unroll
    for (int qi = 0; qi < 2; qi++) {
        const bf16* qp = qb + ((long)bh * T_ + q0 + qi * 64 + w * 16 + ln) * D_;
        qf[qi][0] = *(const bf16x8*)(qp + g * 8);
        qf[qi][1] = *(const bf16x8*)(qp + 32 + g * 8);
    }

    bf16x8 ones;
#pragma unroll
    for (int i = 0; i < 8; i++) ones[i] = 0x3F80;    // bf16 1.0

    f32x4 o[2][4] = {};
    f32x4 l[2] = {};
    short* myP = &Ps[w * 16 * 64];

    const int c0 = tid, c1 = tid + 256;
    const int k_key0 = c0 >> 3, k_c80 = c0 & 7;
    const int k_key1 = c1 >> 3, k_c81 = c1 & 7;

    const int kend = q0 + 128;
    for (int k0 = 0; k0 < kend; k0 += 64) {
        const bf16x8 kr0 = *(const bf16x8*)&kb[((long)bh * T_ + k0 + k_key0) * D_ + k_c80 * 8];
        const bf16x8 kr1 = *(const bf16x8*)&kb[((long)bh * T_ + k0 + k_key1) * D_ + k_c81 * 8];
        const bf16x8 vr0 = *(const bf16x8*)&vb[((long)bh * D_ + k_key0) * T_ + k0 + k_c80 * 8];
        const bf16x8 vr1 = *(const bf16x8*)&vb[((long)bh * D_ + k_key1) * T_ + k0 + k_c81 * 8];
        __syncthreads();   // previous tile's Ks/Vs reads done
        *(bf16x8*)&Ks[k_key0 * 64 + (k_c80 ^ (k_key0 & 7)) * 8] = kr0;
        *(bf16x8*)&Ks[k_key1 * 64 + (k_c81 ^ (k_key1 & 7)) * 8] = kr1;
        *(bf16x8*)&Vs[k_key0 * 64 + (k_c80 ^ (k_key0 & 7)) * 8] = vr0;
        *(bf16x8*)&Vs[k_key1 * 64 + (k_c81 ^ (k_key1 & 7)) * 8] = vr1;
        __syncthreads();   // staging visible

#pragma unroll
        for (int qi = 0; qi < 2; qi++) {
            if (k0 > q0 + qi * 64 + 63) continue;   // tile fully masked (uniform)

            // ---- S = Q K^T : C-layout row=q local g*4+r, col=key kj*16+ln ----
            f32x4 s[4] = {};
#pragma unroll
            for (int kj = 0; kj < 4; kj++) {
                const int krow = kj * 16 + ln;
                const bf16x8 kf0 = *(const bf16x8*)&Ks[krow * 64 + ((0 + g) ^ (krow & 7)) * 8];
                s[kj] = __builtin_amdgcn_mfma_f32_16x16x32_bf16(qf[qi][0], kf0, s[kj], 0, 0, 0);
                const bf16x8 kf1 = *(const bf16x8*)&Ks[krow * 64 + ((4 + g) ^ (krow & 7)) * 8];
                s[kj] = __builtin_amdgcn_mfma_f32_16x16x32_bf16(qf[qi][1], kf1, s[kj], 0, 0, 0);
            }

            // ---- P = exp(S/32) with causal mask (no running max: |S/32| small) ----
            const int rowg = q0 + qi * 64 + w * 16 + g * 4;   // + r
#pragma unroll
            for (int kj = 0; kj < 4; kj++) {
                const int key = k0 + kj * 16 + ln;
#pragma unroll
                for (int r = 0; r < 4; r++) {
                    float p = __expf(s[kj][r] * 0.03125f);    // scale = C^-0.5 = 1/32
                    p = (key <= rowg + r) ? p : 0.f;
                    const int prow = g * 4 + r;
                    const int pc8 = (kj * 2 + (ln >> 3)) ^ (prow & 7);
                    myP[prow * 64 + pc8 * 8 + (ln & 7)] = f2bs(p);
                }
            }
            asm volatile("s_waitcnt lgkmcnt(0)" ::: "memory");  // wave-local P RAW

            // ---- P frags as B-operand: B[k=key][n=q=ln] = P[ln][key] ----
            const bf16x8 pf0 = *(const bf16x8*)&myP[ln * 64 + ((0 + g) ^ (ln & 7)) * 8];
            const bf16x8 pf1 = *(const bf16x8*)&myP[ln * 64 + ((4 + g) ^ (ln & 7)) * 8];

            // l += ones * P  (C-layout col=q=ln, all rows identical)
            l[qi] = __builtin_amdgcn_mfma_f32_16x16x32_bf16(ones, pf0, l[qi], 0, 0, 0);
            l[qi] = __builtin_amdgcn_mfma_f32_16x16x32_bf16(ones, pf1, l[qi], 0, 0, 0);

            // ---- O^T += V^T P^T : A = V^T frag from Vs[d][key], B = pf ----
#pragma unroll
            for (int nb = 0; nb < 4; nb++) {
                const int drow = nb * 16 + ln;
                const bf16x8 vf0 = *(const bf16x8*)&Vs[drow * 64 + ((0 + g) ^ (drow & 7)) * 8];
                o[qi][nb] = __builtin_amdgcn_mfma_f32_16x16x32_bf16(vf0, pf0, o[qi][nb], 0, 0, 0);
                const bf16x8 vf1 = *(const bf16x8*)&Vs[drow * 64 + ((4 + g) ^ (drow & 7)) * 8];
                o[qi][nb] = __builtin_amdgcn_mfma_f32_16x16x32_bf16(vf1, pf1, o[qi][nb], 0, 0, 0);
            }
        }
    }

    // ---- epilogue: O^T C-layout row=d local (g*4+r), col=q=ln; divide by l, store 8B ----
#pragma unroll
    for (int qi = 0; qi < 2; qi++) {
        const float invl = 1.f / l[qi][0];
        const int q = q0 + qi * 64 + w * 16 + ln;
#pragma unroll
        for (int nb = 0; nb < 4; nb++) {
            bf16x4 pk;
#pragma unroll
            for (int r = 0; r < 4; r++) pk[r] = f2bs(o[qi][nb][r] * invl);
            *(bf16x4*)&att[((long)b * T_ + q) * C_ + h * D_ + nb * 16 + g * 4] = pk;
        }
    }
}

// ---------------- launch ----------------
extern "C" void kernel_launch(void* const* d_in, const int* in_sizes, int n_in,
                              void* d_out, int out_size, void* d_ws, size_t ws_size,
                              hipStream_t stream) {
    const float* x     = (const float*)d_in[0];   // [B,T,C] fp32
    const float* Wqkv  = (const float*)d_in[1];   // [C,3C]  fp32
    const float* Wproj = (const float*)d_in[2];   // [C,C]   fp32
    float* out = (float*)d_out;                   // [B,T,C] fp32

    char* ws = (char*)d_ws;
    bf16* wqkv_t  = (bf16*)(ws);                 // [3072,1024] bf16  6291456 B
    bf16* wproj_t = (bf16*)(ws + 6291456);       // [1024,1024] bf16  2097152 B
    bf16* qb      = (bf16*)(ws + 8388608);       // [B,H,T,D]   bf16 16777216 B
    bf16* kb      = (bf16*)(ws + 25165824);      // [B,H,T,D]   bf16 16777216 B
    bf16* vb      = (bf16*)(ws + 41943040);      // [B,H,D,T]   bf16 16777216 B
    bf16* att     = (bf16*)(ws + 58720256);      // [B,T,C]     bf16 16777216 B (end 75497472)
    bf16* xb      = att;                         // alias: xb dead before flash writes att
    (void)ws_size; (void)in_sizes; (void)n_in; (void)out_size;

    cvt_x<<<dim3(M_ * C_ / (256 * 8)), dim3(256), 0, stream>>>(x, xb);
    transpose_k<<<dim3(NQKV / 32, C_ / 32), dim3(256), 0, stream>>>(Wqkv, wqkv_t, C_, NQKV);
    transpose_k<<<dim3(C_ / 32, C_ / 32), dim3(256), 0, stream>>>(Wproj, wproj_t, C_, C_);
    gemm_bt<0><<<dim3(NQKV / 128, M_ / 128), dim3(256), 0, stream>>>(
        xb, wqkv_t, (float*)nullptr, qb, kb, vb, C_, NQKV);
    flash<<<dim3(T_ / 128, B_ * H_), dim3(256), 0, stream>>>(qb, kb, vb, att);
    gemm_bt<1><<<dim3(C_ / 128, M_ / 128), dim3(256), 0, stream>>>(
        att, wproj_t, out, (bf16*)nullptr, (bf16*)nullptr, (bf16*)nullptr, C_, C_);
}

// Round 6
// 305.946 us; speedup vs baseline: 1.8074x; 1.1163x over previous
//
#include <hip/hip_runtime.h>
#include <hip/hip_bf16.h>

// Problem constants
#define B_   4
#define T_   2048
#define C_   1024
#define H_   16
#define D_   64
#define NQKV 3072
#define M_   (B_*T_)

typedef __attribute__((ext_vector_type(8))) short bf16x8;   // 8 bf16 = 4 VGPR (MFMA A/B frag)
typedef __attribute__((ext_vector_type(4))) short bf16x4;   // 8B packed store
typedef __attribute__((ext_vector_type(4))) float f32x4;    // MFMA C/D frag
typedef __hip_bfloat16 bf16;

__device__ inline short f2bs(float f) {
    bf16 h = __float2bfloat16(f);
    return *(short*)&h;
}

// async global->LDS, 16B per lane. LDS dest must be wave-uniform base + lane*16.
__device__ inline void async_ld16(const bf16* g, bf16* l) {
    __builtin_amdgcn_global_load_lds(
        (const __attribute__((address_space(1))) void*)g,
        (__attribute__((address_space(3))) void*)l, 16, 0, 0);
}

// ---------------- x fp32 -> bf16 (8 elem/thread) ----------------
__global__ __launch_bounds__(256) void cvt_x(const float* __restrict__ in,
                                             bf16* __restrict__ out) {
    const long i = ((long)blockIdx.x * 256 + threadIdx.x) * 8;
    const float4 a = *(const float4*)(in + i);
    const float4 b = *(const float4*)(in + i + 4);
    bf16x8 o;
    o[0] = f2bs(a.x); o[1] = f2bs(a.y); o[2] = f2bs(a.z); o[3] = f2bs(a.w);
    o[4] = f2bs(b.x); o[5] = f2bs(b.y); o[6] = f2bs(b.z); o[7] = f2bs(b.w);
    *(bf16x8*)(out + i) = o;
}

// ---------------- weight transpose (fp32 in -> bf16 out): out[c][r] = in[r][c] ----
__global__ __launch_bounds__(256) void transpose_k(const float* __restrict__ in,
                                                   bf16* __restrict__ out,
                                                   int R, int Ccol) {
    __shared__ short t[32][33];
    const int x = threadIdx.x & 31, y = threadIdx.x >> 5;  // 32 x 8
    const int r0 = blockIdx.y * 32, c0 = blockIdx.x * 32;
#pragma unroll
    for (int i = 0; i < 4; i++)
        t[y + 8*i][x] = f2bs(in[(long)(r0 + y + 8*i) * Ccol + c0 + x]);
    __syncthreads();
#pragma unroll
    for (int i = 0; i < 4; i++)
        ((short*)out)[(long)(c0 + y + 8*i) * R + r0 + x] = t[x][y + 8*i];
}

// ---------------- V transpose per head: [bh][t][d] -> [bh][d][t] (bf16) ----------
__global__ __launch_bounds__(256) void transpose_v(const bf16* __restrict__ in,
                                                   bf16* __restrict__ out) {
    __shared__ short t[32][33];
    const int x = threadIdx.x & 31, y = threadIdx.x >> 5;  // 32 x 8
    const int t0 = blockIdx.x * 32, d0 = blockIdx.y * 32;
    const long base = (long)blockIdx.z * T_ * D_;
#pragma unroll
    for (int i = 0; i < 4; i++)
        t[y + 8*i][x] = ((const short*)in)[base + (long)(t0 + y + 8*i) * D_ + d0 + x];
    __syncthreads();
#pragma unroll
    for (int i = 0; i < 4; i++)
        ((short*)out)[base + (long)(d0 + y + 8*i) * T_ + t0 + x] = t[x][y + 8*i];
}

// ---------------- GEMM: C[M,N] = A[M,K] * Bt[N,K]^T  (m97: global_load_lds) -------
// MODE 0: epilogue scatters bf16 to k/q/v0 buffers (split order k,q,v!); V coalesced [B,H,T,D]
// MODE 1: epilogue stores fp32 to outp[M,N]
template<int MODE>
__global__ __launch_bounds__(256) void gemm_bt(const bf16* __restrict__ A,
                                               const bf16* __restrict__ Bt,
                                               float* __restrict__ outp,
                                               bf16* __restrict__ qb,
                                               bf16* __restrict__ kb,
                                               bf16* __restrict__ vb,
                                               int K, int N) {
    __shared__ __align__(16) bf16 As[128 * 32];
    __shared__ __align__(16) bf16 Bs[128 * 32];
    const int tid  = threadIdx.x;
    const int w    = tid >> 6, lane = tid & 63;
    const int g    = lane >> 4, ln = lane & 15;
    const int m0   = blockIdx.y * 128, n0 = blockIdx.x * 128;
    const int wm   = w & 1, wn = w >> 1;           // wave quadrant (2x2 of 64x64)
    const int srow = lane >> 2;                    // 0..15 (16 rows per wave-issue)
    const int scol = (lane & 3) * 8;               // 0/8/16/24

    f32x4 acc[4][4] = {};

    for (int k0 = 0; k0 < K; k0 += 32) {
#pragma unroll
        for (int i = 0; i < 2; i++) {
            const int r = w * 32 + i * 16 + srow;
            async_ld16(A  + (long)(m0 + r) * K + k0 + scol, &As[r * 32 + scol]);
            async_ld16(Bt + (long)(n0 + r) * K + k0 + scol, &Bs[r * 32 + scol]);
        }
        __syncthreads();   // drains vmcnt -> staging complete & visible

        bf16x8 af[4], bfr[4];
#pragma unroll
        for (int i = 0; i < 4; i++)
            af[i]  = *(const bf16x8*)&As[(wm * 64 + i * 16 + ln) * 32 + g * 8];
#pragma unroll
        for (int j = 0; j < 4; j++)
            bfr[j] = *(const bf16x8*)&Bs[(wn * 64 + j * 16 + ln) * 32 + g * 8];
#pragma unroll
        for (int i = 0; i < 4; i++)
#pragma unroll
            for (int j = 0; j < 4; j++)
                acc[i][j] = __builtin_amdgcn_mfma_f32_16x16x32_bf16(af[i], bfr[j], acc[i][j], 0, 0, 0);
        __syncthreads();   // fragment reads done before next tile's DMA overwrites
    }

#pragma unroll
    for (int i = 0; i < 4; i++) {
#pragma unroll
        for (int j = 0; j < 4; j++) {
#pragma unroll
            for (int r = 0; r < 4; r++) {
                const int row = m0 + wm * 64 + i * 16 + g * 4 + r;   // C/D: row = quad*4+reg
                const int col = n0 + wn * 64 + j * 16 + ln;          // C/D: col = lane&15
                if (MODE == 1) {
                    outp[(long)row * N + col] = acc[i][j][r];        // fp32 output
                } else {
                    const bf16 val = __float2bfloat16(acc[i][j][r]);
                    const int b = row >> 11, t = row & (T_ - 1);
                    const int seg = col >> 10;                 // 0:K 1:Q 2:V (split order!)
                    const int c = col & (C_ - 1), h = c >> 6, d = c & 63;
                    if (seg == 0)
                        kb[(((long)(b * H_ + h)) * T_ + t) * D_ + d] = val;
                    else if (seg == 1)
                        qb[(((long)(b * H_ + h)) * T_ + t) * D_ + d] = val;
                    else  // V coalesced [B,H,T,D]; transposed later by transpose_v
                        vb[(((long)(b * H_ + h)) * T_ + t) * D_ + d] = val;
                }
            }
        }
    }
}

// ---------------- flash v3: KT=128, CU-class-balanced 1-D grid ----------------
// 1024 blocks, 256 thr = 4 waves. Wave w: q rows {q0+qi*64+w*16+0..15}, qi=0,1.
// LDS: Ks 16KB + Vs 16KB + Ps 8KB = 40KB -> 4 blocks/CU (matches 1024/256 grid).
__global__ __launch_bounds__(256, 4) void flash(const bf16* __restrict__ qb,
                                                const bf16* __restrict__ kb,
                                                const bf16* __restrict__ vbT,
                                                bf16* __restrict__ att) {
    __shared__ __align__(16) short Ks[128 * 64];     // [key][d]  chunk^=key&7
    __shared__ __align__(16) short Vs[64 * 128];     // [d][key]  chunk^=d&7
    __shared__ __align__(16) short Ps[4 * 16 * 64];  // per-wave [qrow][key] swizzled
    const int tid = threadIdx.x, w = tid >> 6, lane = tid & 63;
    const int g = lane >> 4, ln = lane & 15;

    // CU-aware balanced mapping: same-CU blocks (lin = c mod 256) get classes summing 30
    const int lin = blockIdx.x;
    const int j = lin & 255, s = lin >> 8;
    const int ctab[4][4] = {{0,15,7,8},{1,14,6,9},{2,13,5,10},{3,12,4,11}};
    const int qblk = ctab[j & 3][s];
    const int bh = j >> 2;
    const int q0 = qblk * 128;
    const int b = bh >> 4, h = bh & 15;

    // Q fragments (A-layout): qf[qi][chunk], lane = Q[q0+qi*64+w*16+ln][chunk*32+g*8+j]
    bf16x8 qf[2][2];
#pragma unroll
    for (int qi = 0; qi < 2; qi++) {
        const bf16* qp = qb + ((long)bh * T_ + q0 + qi * 64 + w * 16 + ln) * D_;
        qf[qi][0] = *(const bf16x8*)(qp + g * 8);
        qf[qi][1] = *(const bf16x8*)(qp + 32 + g * 8);
    }

    bf16x8 ones;
#pragma unroll
    for (int i = 0; i < 8; i++) ones[i] = 0x3F80;    // bf16 1.0

    f32x4 o[2][4] = {};
    f32x4 l[2] = {};
    short* myP = &Ps[w * 16 * 64];

    const int kend = q0 + 128;
    for (int k0 = 0; k0 < kend; k0 += 128) {
        // stage K (128x64) and V^T (64x128): 4 chunks each per thread, coalesced
        bf16x8 kr[4], vr[4];
#pragma unroll
        for (int i = 0; i < 4; i++) {
            const int cc = i * 256 + tid;
            kr[i] = *(const bf16x8*)&kb [((long)bh * T_ + k0 + (cc >> 3)) * D_ + (cc & 7) * 8];
            vr[i] = *(const bf16x8*)&vbT[((long)bh * D_ + (cc >> 4)) * T_ + k0 + (cc & 15) * 8];
        }
        __syncthreads();   // previous tile's reads done
#pragma unroll
        for (int i = 0; i < 4; i++) {
            const int cc = i * 256 + tid;
            const int key = cc >> 3, c8 = cc & 7;
            *(bf16x8*)&Ks[key * 64 + (c8 ^ (key & 7)) * 8] = kr[i];
            const int d = cc >> 4, c16 = cc & 15;
            *(bf16x8*)&Vs[d * 128 + (c16 ^ (d & 7)) * 8] = vr[i];
        }
        __syncthreads();   // staging visible

#pragma unroll
        for (int qi = 0; qi < 2; qi++) {
            const int rowmax = q0 + qi * 64 + 63;
#pragma unroll
            for (int h2 = 0; h2 < 2; h2++) {
                const int kbase = k0 + h2 * 64;
                if (kbase > rowmax) continue;    // half fully masked (uniform)

                // ---- S = Q K^T : C-layout row=q local g*4+r, col=key kj*16+ln ----
                f32x4 sarr[4] = {};
#pragma unroll
                for (int kj = 0; kj < 4; kj++) {
                    const int krow = h2 * 64 + kj * 16 + ln;
                    const bf16x8 kf0 = *(const bf16x8*)&Ks[krow * 64 + ((0 + g) ^ (krow & 7)) * 8];
                    sarr[kj] = __builtin_amdgcn_mfma_f32_16x16x32_bf16(qf[qi][0], kf0, sarr[kj], 0, 0, 0);
                    const bf16x8 kf1 = *(const bf16x8*)&Ks[krow * 64 + ((4 + g) ^ (krow & 7)) * 8];
                    sarr[kj] = __builtin_amdgcn_mfma_f32_16x16x32_bf16(qf[qi][1], kf1, sarr[kj], 0, 0, 0);
                }

                // ---- P = exp(S/32) with causal mask (no running max: |S/32| small) ----
                const int rowg = q0 + qi * 64 + w * 16 + g * 4;   // + r
#pragma unroll
                for (int kj = 0; kj < 4; kj++) {
                    const int key = kbase + kj * 16 + ln;
#pragma unroll
                    for (int r = 0; r < 4; r++) {
                        float p = __expf(sarr[kj][r] * 0.03125f);  // scale = C^-0.5 = 1/32
                        p = (key <= rowg + r) ? p : 0.f;
                        const int prow = g * 4 + r;
                        const int pc8 = (kj * 2 + (ln >> 3)) ^ (prow & 7);
                        myP[prow * 64 + pc8 * 8 + (ln & 7)] = f2bs(p);
                    }
                }
                asm volatile("s_waitcnt lgkmcnt(0)" ::: "memory");  // wave-local P RAW

                // ---- P frags as B-operand: B[k=key][n=q=ln] = P[ln][key] ----
                const bf16x8 pf0 = *(const bf16x8*)&myP[ln * 64 + ((0 + g) ^ (ln & 7)) * 8];
                const bf16x8 pf1 = *(const bf16x8*)&myP[ln * 64 + ((4 + g) ^ (ln & 7)) * 8];

                // l += ones * P  (C-layout col=q=ln, all rows identical)
                l[qi] = __builtin_amdgcn_mfma_f32_16x16x32_bf16(ones, pf0, l[qi], 0, 0, 0);
                l[qi] = __builtin_amdgcn_mfma_f32_16x16x32_bf16(ones, pf1, l[qi], 0, 0, 0);

                // ---- O^T += V^T P^T : A = V^T frag from Vs[d][key], B = pf ----
#pragma unroll
                for (int nb = 0; nb < 4; nb++) {
                    const int drow = nb * 16 + ln;
                    const bf16x8 vf0 = *(const bf16x8*)&Vs[drow * 128 + ((h2 * 8 + 0 + g) ^ (drow & 7)) * 8];
                    o[qi][nb] = __builtin_amdgcn_mfma_f32_16x16x32_bf16(vf0, pf0, o[qi][nb], 0, 0, 0);
                    const bf16x8 vf1 = *(const bf16x8*)&Vs[drow * 128 + ((h2 * 8 + 4 + g) ^ (drow & 7)) * 8];
                    o[qi][nb] = __builtin_amdgcn_mfma_f32_16x16x32_bf16(vf1, pf1, o[qi][nb], 0, 0, 0);
                }
            }
        }
    }

    // ---- epilogue: O^T C-layout row=d local (g*4+r), col=q=ln; divide by l, store 8B ----
#pragma unroll
    for (int qi = 0; qi < 2; qi++) {
        const float invl = 1.f / l[qi][0];
        const int q = q0 + qi * 64 + w * 16 + ln;
#pragma unroll
        for (int nb = 0; nb < 4; nb++) {
            bf16x4 pk;
#pragma unroll
            for (int r = 0; r < 4; r++) pk[r] = f2bs(o[qi][nb][r] * invl);
            *(bf16x4*)&att[((long)b * T_ + q) * C_ + h * D_ + nb * 16 + g * 4] = pk;
        }
    }
}

// ---------------- launch ----------------
extern "C" void kernel_launch(void* const* d_in, const int* in_sizes, int n_in,
                              void* d_out, int out_size, void* d_ws, size_t ws_size,
                              hipStream_t stream) {
    const float* x     = (const float*)d_in[0];   // [B,T,C] fp32
    const float* Wqkv  = (const float*)d_in[1];   // [C,3C]  fp32
    const float* Wproj = (const float*)d_in[2];   // [C,C]   fp32
    float* out = (float*)d_out;                   // [B,T,C] fp32

    // Liveness-planned workspace (75.5 MB total, unchanged):
    //  gemm0 live: {xb, wqkv_t, wproj_t, qb, kb, vb0}
    //  vbT aliases xb (xb dead after gemm0); att aliases vb0 (dead after transpose_v)
    char* ws = (char*)d_ws;
    bf16* wqkv_t  = (bf16*)(ws);                 // [3072,1024] bf16  6291456 B
    bf16* wproj_t = (bf16*)(ws + 6291456);       // [1024,1024] bf16  2097152 B
    bf16* qb      = (bf16*)(ws + 8388608);       // [B,H,T,D]   bf16 16777216 B
    bf16* kb      = (bf16*)(ws + 25165824);      // [B,H,T,D]   bf16 16777216 B
    bf16* vb0     = (bf16*)(ws + 41943040);      // [B,H,T,D]   bf16 16777216 B
    bf16* xb      = (bf16*)(ws + 58720256);      // [B,T,C]     bf16 16777216 B
    bf16* vbT     = xb;                          // alias (after gemm0)
    bf16* att     = vb0;                         // alias (after transpose_v)
    (void)ws_size; (void)in_sizes; (void)n_in; (void)out_size;

    cvt_x<<<dim3(M_ * C_ / (256 * 8)), dim3(256), 0, stream>>>(x, xb);
    transpose_k<<<dim3(NQKV / 32, C_ / 32), dim3(256), 0, stream>>>(Wqkv, wqkv_t, C_, NQKV);
    transpose_k<<<dim3(C_ / 32, C_ / 32), dim3(256), 0, stream>>>(Wproj, wproj_t, C_, C_);
    gemm_bt<0><<<dim3(NQKV / 128, M_ / 128), dim3(256), 0, stream>>>(
        xb, wqkv_t, (float*)nullptr, qb, kb, vb0, C_, NQKV);
    transpose_v<<<dim3(T_ / 32, D_ / 32, B_ * H_), dim3(256), 0, stream>>>(vb0, vbT);
    flash<<<dim3(1024), dim3(256), 0, stream>>>(qb, kb, vbT, att);
    gemm_bt<1><<<dim3(C_ / 128, M_ / 128), dim3(256), 0, stream>>>(
        att, wproj_t, out, (bf16*)nullptr, (bf16*)nullptr, (bf16*)nullptr, C_, C_);
}

// Round 7
// 279.124 us; speedup vs baseline: 1.9811x; 1.0961x over previous
//
#include <hip/hip_runtime.h>
#include <hip/hip_bf16.h>

// Problem constants
#define B_   4
#define T_   2048
#define C_   1024
#define H_   16
#define D_   64
#define NQKV 3072
#define M_   (B_*T_)

typedef __attribute__((ext_vector_type(8))) short bf16x8;   // 8 bf16 = 4 VGPR (MFMA A/B frag)
typedef __attribute__((ext_vector_type(4))) short bf16x4;   // 8B packed store
typedef __attribute__((ext_vector_type(4))) float f32x4;    // MFMA C/D frag
typedef __hip_bfloat16 bf16;

__device__ inline short f2bs(float f) {
    bf16 h = __float2bfloat16(f);
    return *(short*)&h;
}

// async global->LDS, 16B per lane. LDS dest must be wave-uniform base + lane*16.
__device__ inline void async_ld16(const bf16* g, bf16* l) {
    __builtin_amdgcn_global_load_lds(
        (const __attribute__((address_space(1))) void*)g,
        (__attribute__((address_space(3))) void*)l, 16, 0, 0);
}

// ---------------- fused prep: cvt_x (blocks 0..4095), Wqkv^T (4096..7167),
//                  Wproj^T (7168..8191) ----------------
__global__ __launch_bounds__(256) void prep(const float* __restrict__ x,
                                            const float* __restrict__ Wqkv,
                                            const float* __restrict__ Wproj,
                                            bf16* __restrict__ xb,
                                            bf16* __restrict__ wqkv_t,
                                            bf16* __restrict__ wproj_t) {
    __shared__ short t[32][33];
    const int bid = blockIdx.x;
    if (bid < 4096) {
        const long i = ((long)bid * 256 + threadIdx.x) * 8;
        const float4 a = *(const float4*)(x + i);
        const float4 bq = *(const float4*)(x + i + 4);
        bf16x8 o;
        o[0] = f2bs(a.x); o[1] = f2bs(a.y); o[2] = f2bs(a.z); o[3] = f2bs(a.w);
        o[4] = f2bs(bq.x); o[5] = f2bs(bq.y); o[6] = f2bs(bq.z); o[7] = f2bs(bq.w);
        *(bf16x8*)(xb + i) = o;
        return;
    }
    const float* in;  bf16* out;  int R, Ccol, r0, c0;
    if (bid < 7168) {
        const int b2 = bid - 4096;            // Wqkv: [C,3C] -> [3C,C]
        in = Wqkv; out = wqkv_t; R = C_; Ccol = NQKV;
        c0 = (b2 % 96) * 32; r0 = (b2 / 96) * 32;
    } else {
        const int b3 = bid - 7168;            // Wproj: [C,C] -> [C,C]^T
        in = Wproj; out = wproj_t; R = C_; Ccol = C_;
        c0 = (b3 % 32) * 32; r0 = (b3 / 32) * 32;
    }
    const int xx = threadIdx.x & 31, yy = threadIdx.x >> 5;  // 32 x 8
#pragma unroll
    for (int i = 0; i < 4; i++)
        t[yy + 8*i][xx] = f2bs(in[(long)(r0 + yy + 8*i) * Ccol + c0 + xx]);
    __syncthreads();
#pragma unroll
    for (int i = 0; i < 4; i++)
        ((short*)out)[(long)(c0 + yy + 8*i) * R + r0 + xx] = t[xx][yy + 8*i];
}

// ---------------- V transpose per head: [bh][t][d] -> [bh][d][t] (bf16) ----------
__global__ __launch_bounds__(256) void transpose_v(const bf16* __restrict__ in,
                                                   bf16* __restrict__ out) {
    __shared__ short t[32][33];
    const int x = threadIdx.x & 31, y = threadIdx.x >> 5;  // 32 x 8
    const int t0 = blockIdx.x * 32, d0 = blockIdx.y * 32;
    const long base = (long)blockIdx.z * T_ * D_;
#pragma unroll
    for (int i = 0; i < 4; i++)
        t[y + 8*i][x] = ((const short*)in)[base + (long)(t0 + y + 8*i) * D_ + d0 + x];
    __syncthreads();
#pragma unroll
    for (int i = 0; i < 4; i++)
        ((short*)out)[base + (long)(d0 + y + 8*i) * T_ + t0 + x] = t[x][y + 8*i];
}

// ---------------- GEMM: C[M,N] = A[M,K] * Bt[N,K]^T  (m97: global_load_lds) -------
// MODE 0: epilogue scatters bf16 to k/q/v0 buffers (split k,q,v!); Q pre-scaled 1/32
// MODE 1: epilogue stores fp32 to outp[M,N]
template<int MODE>
__global__ __launch_bounds__(256) void gemm_bt(const bf16* __restrict__ A,
                                               const bf16* __restrict__ Bt,
                                               float* __restrict__ outp,
                                               bf16* __restrict__ qb,
                                               bf16* __restrict__ kb,
                                               bf16* __restrict__ vb,
                                               int K, int N) {
    __shared__ __align__(16) bf16 As[128 * 32];
    __shared__ __align__(16) bf16 Bs[128 * 32];
    const int tid  = threadIdx.x;
    const int w    = tid >> 6, lane = tid & 63;
    const int g    = lane >> 4, ln = lane & 15;
    const int m0   = blockIdx.y * 128, n0 = blockIdx.x * 128;
    const int wm   = w & 1, wn = w >> 1;           // wave quadrant (2x2 of 64x64)
    const int srow = lane >> 2;                    // 0..15 (16 rows per wave-issue)
    const int scol = (lane & 3) * 8;               // 0/8/16/24

    f32x4 acc[4][4] = {};

    for (int k0 = 0; k0 < K; k0 += 32) {
#pragma unroll
        for (int i = 0; i < 2; i++) {
            const int r = w * 32 + i * 16 + srow;
            async_ld16(A  + (long)(m0 + r) * K + k0 + scol, &As[r * 32 + scol]);
            async_ld16(Bt + (long)(n0 + r) * K + k0 + scol, &Bs[r * 32 + scol]);
        }
        __syncthreads();   // drains vmcnt -> staging complete & visible

        bf16x8 af[4], bfr[4];
#pragma unroll
        for (int i = 0; i < 4; i++)
            af[i]  = *(const bf16x8*)&As[(wm * 64 + i * 16 + ln) * 32 + g * 8];
#pragma unroll
        for (int j = 0; j < 4; j++)
            bfr[j] = *(const bf16x8*)&Bs[(wn * 64 + j * 16 + ln) * 32 + g * 8];
#pragma unroll
        for (int i = 0; i < 4; i++)
#pragma unroll
            for (int j = 0; j < 4; j++)
                acc[i][j] = __builtin_amdgcn_mfma_f32_16x16x32_bf16(af[i], bfr[j], acc[i][j], 0, 0, 0);
        __syncthreads();   // fragment reads done before next tile's DMA overwrites
    }

#pragma unroll
    for (int i = 0; i < 4; i++) {
#pragma unroll
        for (int j = 0; j < 4; j++) {
#pragma unroll
            for (int r = 0; r < 4; r++) {
                const int row = m0 + wm * 64 + i * 16 + g * 4 + r;   // C/D: row = quad*4+reg
                const int col = n0 + wn * 64 + j * 16 + ln;          // C/D: col = lane&15
                if (MODE == 1) {
                    outp[(long)row * N + col] = acc[i][j][r];        // fp32 output
                } else {
                    const int b = row >> 11, t = row & (T_ - 1);
                    const int seg = col >> 10;                 // 0:K 1:Q 2:V (split order!)
                    const int c = col & (C_ - 1), h = c >> 6, d = c & 63;
                    if (seg == 0)
                        kb[(((long)(b * H_ + h)) * T_ + t) * D_ + d] = __float2bfloat16(acc[i][j][r]);
                    else if (seg == 1)   // Q pre-scaled by C^-0.5 = 1/32 (exact in bf16)
                        qb[(((long)(b * H_ + h)) * T_ + t) * D_ + d] = __float2bfloat16(acc[i][j][r] * 0.03125f);
                    else  // V coalesced [B,H,T,D]; transposed later by transpose_v
                        vb[(((long)(b * H_ + h)) * T_ + t) * D_ + d] = __float2bfloat16(acc[i][j][r]);
                }
            }
        }
    }
}

// ---------------- flash v4: uniform paired q-tiles, shared staging ----------------
// grid 1024: lin = p*64+... -> bh = lin&63 (pins bh to XCD lin%8), p = lin>>6.
// Block owns q64-tiles {p, 31-p}: 33 subtiles + 9..16 stagings -> uniform cost.
// Wave w handles q rows q0 + w*16 + 0..15 of each tile.
__device__ inline void subtile(const bf16x8& qf0, const bf16x8& qf1,
                               f32x4* o, f32x4& l,
                               const short* Ks, const short* Vs, short* myP,
                               int q0, int kbase, int h2, int w, int g, int ln,
                               const bf16x8& ones) {
    f32x4 s[4] = {};
#pragma unroll
    for (int kj = 0; kj < 4; kj++) {
        const int krow = h2 * 64 + kj * 16 + ln;
        const bf16x8 kf0 = *(const bf16x8*)&Ks[krow * 64 + ((0 + g) ^ (krow & 7)) * 8];
        s[kj] = __builtin_amdgcn_mfma_f32_16x16x32_bf16(qf0, kf0, s[kj], 0, 0, 0);
        const bf16x8 kf1 = *(const bf16x8*)&Ks[krow * 64 + ((4 + g) ^ (krow & 7)) * 8];
        s[kj] = __builtin_amdgcn_mfma_f32_16x16x32_bf16(qf1, kf1, s[kj], 0, 0, 0);
    }
    const int rowg = q0 + w * 16 + g * 4;   // + r
    if (kbase == q0) {                      // diagonal sub-tile: causal mask
#pragma unroll
        for (int kj = 0; kj < 4; kj++) {
            const int key = kbase + kj * 16 + ln;
#pragma unroll
            for (int r = 0; r < 4; r++) {
                float p = __expf(s[kj][r]);            // Q pre-scaled: no mul here
                p = (key <= rowg + r) ? p : 0.f;
                const int prow = g * 4 + r;
                const int pc8 = (kj * 2 + (ln >> 3)) ^ (prow & 7);
                myP[prow * 64 + pc8 * 8 + (ln & 7)] = f2bs(p);
            }
        }
    } else {                                // strictly-below-diagonal: unmasked
#pragma unroll
        for (int kj = 0; kj < 4; kj++) {
#pragma unroll
            for (int r = 0; r < 4; r++) {
                const int prow = g * 4 + r;
                const int pc8 = (kj * 2 + (ln >> 3)) ^ (prow & 7);
                myP[prow * 64 + pc8 * 8 + (ln & 7)] = f2bs(__expf(s[kj][r]));
            }
        }
    }
    asm volatile("s_waitcnt lgkmcnt(0)" ::: "memory");   // wave-local P RAW
    const bf16x8 pf0 = *(const bf16x8*)&myP[ln * 64 + ((0 + g) ^ (ln & 7)) * 8];
    const bf16x8 pf1 = *(const bf16x8*)&myP[ln * 64 + ((4 + g) ^ (ln & 7)) * 8];
    l = __builtin_amdgcn_mfma_f32_16x16x32_bf16(ones, pf0, l, 0, 0, 0);
    l = __builtin_amdgcn_mfma_f32_16x16x32_bf16(ones, pf1, l, 0, 0, 0);
#pragma unroll
    for (int nb = 0; nb < 4; nb++) {
        const int drow = nb * 16 + ln;
        const bf16x8 vf0 = *(const bf16x8*)&Vs[drow * 128 + ((h2 * 8 + 0 + g) ^ (drow & 7)) * 8];
        o[nb] = __builtin_amdgcn_mfma_f32_16x16x32_bf16(vf0, pf0, o[nb], 0, 0, 0);
        const bf16x8 vf1 = *(const bf16x8*)&Vs[drow * 128 + ((h2 * 8 + 4 + g) ^ (drow & 7)) * 8];
        o[nb] = __builtin_amdgcn_mfma_f32_16x16x32_bf16(vf1, pf1, o[nb], 0, 0, 0);
    }
}

__global__ __launch_bounds__(256, 4) void flash(const bf16* __restrict__ qb,
                                                const bf16* __restrict__ kb,
                                                const bf16* __restrict__ vbT,
                                                bf16* __restrict__ att) {
    __shared__ __align__(16) short Ks[128 * 64];     // [key][d]  chunk^=key&7
    __shared__ __align__(16) short Vs[64 * 128];     // [d][key]  chunk^=d&7
    __shared__ __align__(16) short Ps[4 * 16 * 64];  // per-wave [qrow][key] swizzled
    const int tid = threadIdx.x, w = tid >> 6, lane = tid & 63;
    const int g = lane >> 4, ln = lane & 15;
    const int lin = blockIdx.x;
    const int bh = lin & 63, p = lin >> 6;
    const int b = bh >> 4, h = bh & 15;
    const int q0A = p * 64, q0B = (31 - p) * 64;

    // Q fragments (A-layout), pre-scaled by 1/32 in gemm0
    const bf16* qpA = qb + ((long)bh * T_ + q0A + w * 16 + ln) * D_;
    const bf16* qpB = qb + ((long)bh * T_ + q0B + w * 16 + ln) * D_;
    const bf16x8 qfA0 = *(const bf16x8*)(qpA + g * 8);
    const bf16x8 qfA1 = *(const bf16x8*)(qpA + 32 + g * 8);
    const bf16x8 qfB0 = *(const bf16x8*)(qpB + g * 8);
    const bf16x8 qfB1 = *(const bf16x8*)(qpB + 32 + g * 8);

    bf16x8 ones;
#pragma unroll
    for (int i = 0; i < 8; i++) ones[i] = 0x3F80;    // bf16 1.0

    f32x4 oA[4] = {}, oB[4] = {};
    f32x4 lA = {}, lB = {};
    short* myP = &Ps[w * 16 * 64];

    const int nstB = (q0B + 64 + 127) >> 7;          // stagings needed (B superset of A)
    for (int s = 0; s < nstB; s++) {
        const int k0 = s * 128;
        // stage K (128x64) and V^T (64x128): 4 chunks each per thread, coalesced
        bf16x8 kr[4], vr[4];
#pragma unroll
        for (int i = 0; i < 4; i++) {
            const int cc = i * 256 + tid;
            kr[i] = *(const bf16x8*)&kb [((long)bh * T_ + k0 + (cc >> 3)) * D_ + (cc & 7) * 8];
            vr[i] = *(const bf16x8*)&vbT[((long)bh * D_ + (cc >> 4)) * T_ + k0 + (cc & 15) * 8];
        }
        __syncthreads();   // previous tile's reads done
#pragma unroll
        for (int i = 0; i < 4; i++) {
            const int cc = i * 256 + tid;
            const int key = cc >> 3, c8 = cc & 7;
            *(bf16x8*)&Ks[key * 64 + (c8 ^ (key & 7)) * 8] = kr[i];
            const int d = cc >> 4, c16 = cc & 15;
            *(bf16x8*)&Vs[d * 128 + (c16 ^ (d & 7)) * 8] = vr[i];
        }
        __syncthreads();   // staging visible

#pragma unroll
        for (int h2 = 0; h2 < 2; h2++) {
            const int kbase = k0 + h2 * 64;
            if (kbase <= q0A + 63)
                subtile(qfA0, qfA1, oA, lA, Ks, Vs, myP, q0A, kbase, h2, w, g, ln, ones);
            if (kbase <= q0B + 63)
                subtile(qfB0, qfB1, oB, lB, Ks, Vs, myP, q0B, kbase, h2, w, g, ln, ones);
        }
    }

    // ---- epilogue: O^T C-layout row=d local (g*4+r), col=q=ln; divide by l ----
#pragma unroll
    for (int ti = 0; ti < 2; ti++) {
        const f32x4* o = ti ? oB : oA;
        const float invl = 1.f / (ti ? lB[0] : lA[0]);
        const int q = (ti ? q0B : q0A) + w * 16 + ln;
#pragma unroll
        for (int nb = 0; nb < 4; nb++) {
            bf16x4 pk;
#pragma unroll
            for (int r = 0; r < 4; r++) pk[r] = f2bs(o[nb][r] * invl);
            *(bf16x4*)&att[((long)b * T_ + q) * C_ + h * D_ + nb * 16 + g * 4] = pk;
        }
    }
}

// ---------------- launch ----------------
extern "C" void kernel_launch(void* const* d_in, const int* in_sizes, int n_in,
                              void* d_out, int out_size, void* d_ws, size_t ws_size,
                              hipStream_t stream) {
    const float* x     = (const float*)d_in[0];   // [B,T,C] fp32
    const float* Wqkv  = (const float*)d_in[1];   // [C,3C]  fp32
    const float* Wproj = (const float*)d_in[2];   // [C,C]   fp32
    float* out = (float*)d_out;                   // [B,T,C] fp32

    // Liveness-planned workspace (75.5 MB):
    //  vbT aliases xb (xb dead after gemm0); att aliases vb0 (dead after transpose_v)
    char* ws = (char*)d_ws;
    bf16* wqkv_t  = (bf16*)(ws);                 // [3072,1024] bf16  6291456 B
    bf16* wproj_t = (bf16*)(ws + 6291456);       // [1024,1024] bf16  2097152 B
    bf16* qb      = (bf16*)(ws + 8388608);       // [B,H,T,D]   bf16 16777216 B
    bf16* kb      = (bf16*)(ws + 25165824);      // [B,H,T,D]   bf16 16777216 B
    bf16* vb0     = (bf16*)(ws + 41943040);      // [B,H,T,D]   bf16 16777216 B
    bf16* xb      = (bf16*)(ws + 58720256);      // [B,T,C]     bf16 16777216 B
    bf16* vbT     = xb;                          // alias (after gemm0)
    bf16* att     = vb0;                         // alias (after transpose_v)
    (void)ws_size; (void)in_sizes; (void)n_in; (void)out_size;

    prep<<<dim3(8192), dim3(256), 0, stream>>>(x, Wqkv, Wproj, xb, wqkv_t, wproj_t);
    gemm_bt<0><<<dim3(NQKV / 128, M_ / 128), dim3(256), 0, stream>>>(
        xb, wqkv_t, (float*)nullptr, qb, kb, vb0, C_, NQKV);
    transpose_v<<<dim3(T_ / 32, D_ / 32, B_ * H_), dim3(256), 0, stream>>>(vb0, vbT);
    flash<<<dim3(1024), dim3(256), 0, stream>>>(qb, kb, vbT, att);
    gemm_bt<1><<<dim3(C_ / 128, M_ / 128), dim3(256), 0, stream>>>(
        att, wproj_t, out, (bf16*)nullptr, (bf16*)nullptr, (bf16*)nullptr, C_, C_);
}

// Round 8
// 248.306 us; speedup vs baseline: 2.2270x; 1.1241x over previous
//
#include <hip/hip_runtime.h>
#include <hip/hip_bf16.h>

// Problem constants
#define B_   4
#define T_   2048
#define C_   1024
#define H_   16
#define D_   64
#define NQKV 3072
#define M_   (B_*T_)

typedef __attribute__((ext_vector_type(8))) short bf16x8;   // 8 bf16 = 4 VGPR (MFMA A/B frag)
typedef __attribute__((ext_vector_type(4))) short bf16x4;   // 8B packed store
typedef __attribute__((ext_vector_type(4))) float f32x4;    // MFMA C/D frag
typedef __hip_bfloat16 bf16;

__device__ inline short f2bs(float f) {
    bf16 h = __float2bfloat16(f);
    return *(short*)&h;
}

// async global->LDS, 16B per lane. LDS dest must be wave-uniform base + lane*16.
__device__ inline void async_ld16(const bf16* g, const short* l) {
    __builtin_amdgcn_global_load_lds(
        (const __attribute__((address_space(1))) void*)g,
        (__attribute__((address_space(3))) void*)l, 16, 0, 0);
}

// ---------------- fused prep: cvt_x (blocks 0..4095), Wqkv^T (4096..7167),
//                  Wproj^T (7168..8191) ----------------
__global__ __launch_bounds__(256) void prep(const float* __restrict__ x,
                                            const float* __restrict__ Wqkv,
                                            const float* __restrict__ Wproj,
                                            bf16* __restrict__ xb,
                                            bf16* __restrict__ wqkv_t,
                                            bf16* __restrict__ wproj_t) {
    __shared__ short t[32][33];
    const int bid = blockIdx.x;
    if (bid < 4096) {
        const long i = ((long)bid * 256 + threadIdx.x) * 8;
        const float4 a = *(const float4*)(x + i);
        const float4 bq = *(const float4*)(x + i + 4);
        bf16x8 o;
        o[0] = f2bs(a.x); o[1] = f2bs(a.y); o[2] = f2bs(a.z); o[3] = f2bs(a.w);
        o[4] = f2bs(bq.x); o[5] = f2bs(bq.y); o[6] = f2bs(bq.z); o[7] = f2bs(bq.w);
        *(bf16x8*)(xb + i) = o;
        return;
    }
    const float* in;  bf16* out;  int R, Ccol, r0, c0;
    if (bid < 7168) {
        const int b2 = bid - 4096;            // Wqkv: [C,3C] -> [3C,C]
        in = Wqkv; out = wqkv_t; R = C_; Ccol = NQKV;
        c0 = (b2 % 96) * 32; r0 = (b2 / 96) * 32;
    } else {
        const int b3 = bid - 7168;            // Wproj: [C,C] -> [C,C]^T
        in = Wproj; out = wproj_t; R = C_; Ccol = C_;
        c0 = (b3 % 32) * 32; r0 = (b3 / 32) * 32;
    }
    const int xx = threadIdx.x & 31, yy = threadIdx.x >> 5;  // 32 x 8
#pragma unroll
    for (int i = 0; i < 4; i++)
        t[yy + 8*i][xx] = f2bs(in[(long)(r0 + yy + 8*i) * Ccol + c0 + xx]);
    __syncthreads();
#pragma unroll
    for (int i = 0; i < 4; i++)
        ((short*)out)[(long)(c0 + yy + 8*i) * R + r0 + xx] = t[xx][yy + 8*i];
}

// ---------------- GEMM: C[M,N] = A[M,K] * Bt[N,K]^T  (BK=64, global_load_lds) -----
// MODE 0: epilogue scatters bf16 to k/q (split k,q,v!); Q pre-scaled 1/32;
//         V-segment blocks (n0>=2048) LDS-transpose and store V^T [B,H,D,T] coalesced.
// MODE 1: epilogue stores fp32 to outp[M,N]
template<int MODE>
__global__ __launch_bounds__(256) void gemm_bt(const bf16* __restrict__ A,
                                               const bf16* __restrict__ Bt,
                                               float* __restrict__ outp,
                                               bf16* __restrict__ qb,
                                               bf16* __restrict__ kb,
                                               bf16* __restrict__ vbT,
                                               int K, int N) {
    // 36 KB union: K-loop uses As(16K)+Bs(16K); V-epilogue reuses as Vt[128][144]
    __shared__ __align__(16) short SMEM[18432];
    short* As = SMEM;            // [128 rows][64 k], chunk c8 stored at slot c8^(row&7)
    short* Bs = SMEM + 8192;
    const int tid  = threadIdx.x;
    const int w    = tid >> 6, lane = tid & 63;
    const int g    = lane >> 4, ln = lane & 15;
    const int m0   = blockIdx.y * 128, n0 = blockIdx.x * 128;
    const int wm   = w & 1, wn = w >> 1;           // wave quadrant (2x2 of 64x64)

    f32x4 acc[4][4] = {};

    for (int k0 = 0; k0 < K; k0 += 64) {
        // stage 128x64 A,B tiles: 4 chunk-issues per thread per operand.
        // LDS slot s -> row=s>>3, slot-chunk=s&7; global chunk = slot^(row&7) (swizzle
        // applied on the GLOBAL side so LDS dest stays uniform-base + lane*16).
#pragma unroll
        for (int i = 0; i < 4; i++) {
            const int s   = w * 256 + i * 64 + lane;
            const int row = s >> 3, c8 = (s & 7) ^ ((s >> 3) & 7);
            async_ld16(A  + (long)(m0 + row) * K + k0 + c8 * 8, &As[s * 8]);
            async_ld16(Bt + (long)(n0 + row) * K + k0 + c8 * 8, &Bs[s * 8]);
        }
        __syncthreads();   // drains vmcnt -> staging complete & visible

#pragma unroll
        for (int kh = 0; kh < 2; kh++) {
            bf16x8 af[4], bfr[4];
#pragma unroll
            for (int i = 0; i < 4; i++)
                af[i]  = *(const bf16x8*)&As[(wm * 64 + i * 16 + ln) * 64 + ((kh * 4 + g) ^ (ln & 7)) * 8];
#pragma unroll
            for (int j = 0; j < 4; j++)
                bfr[j] = *(const bf16x8*)&Bs[(wn * 64 + j * 16 + ln) * 64 + ((kh * 4 + g) ^ (ln & 7)) * 8];
#pragma unroll
            for (int i = 0; i < 4; i++)
#pragma unroll
                for (int j = 0; j < 4; j++)
                    acc[i][j] = __builtin_amdgcn_mfma_f32_16x16x32_bf16(af[i], bfr[j], acc[i][j], 0, 0, 0);
        }
        __syncthreads();   // fragment reads done before next tile's DMA overwrites
    }

    if (MODE == 0 && n0 >= 2048) {
        // ---- V segment: LDS-transpose tile, store V^T [B,H,D,T] with 16B stores ----
        short* Vt = SMEM;                       // [128 d_local][stride 144]
#pragma unroll
        for (int i = 0; i < 4; i++)
#pragma unroll
            for (int j = 0; j < 4; j++)
#pragma unroll
                for (int r = 0; r < 4; r++) {
                    const int tl = wm * 64 + i * 16 + g * 4 + r;   // t within tile
                    const int dl = wn * 64 + j * 16 + ln;          // d_local (2 heads)
                    Vt[dl * 144 + tl] = f2bs(acc[i][j][r]);
                }
        __syncthreads();
        const int b  = m0 >> 11, tb = m0 & (T_ - 1);
        const int h0 = (n0 - 2048) >> 6;
#pragma unroll
        for (int ii = 0; ii < 8; ii++) {
            const int s = ii * 256 + tid;       // 2048 chunks: 128 dl x 16 t-chunks
            const int dl = s >> 4, t16 = s & 15;
            const bf16x8 v = *(const bf16x8*)&Vt[dl * 144 + t16 * 8];
            const int h = h0 + (dl >> 6), d = dl & 63;
            *(bf16x8*)&vbT[(((long)(b * H_ + h)) * D_ + d) * T_ + tb + t16 * 8] = v;
        }
        return;
    }

#pragma unroll
    for (int i = 0; i < 4; i++) {
#pragma unroll
        for (int j = 0; j < 4; j++) {
#pragma unroll
            for (int r = 0; r < 4; r++) {
                const int row = m0 + wm * 64 + i * 16 + g * 4 + r;   // C/D: row = quad*4+reg
                const int col = n0 + wn * 64 + j * 16 + ln;          // C/D: col = lane&15
                if (MODE == 1) {
                    outp[(long)row * N + col] = acc[i][j][r];        // fp32 output
                } else {
                    const int b = row >> 11, t = row & (T_ - 1);
                    const int seg = col >> 10;                 // 0:K 1:Q (V handled above)
                    const int c = col & (C_ - 1), h = c >> 6, d = c & 63;
                    if (seg == 0)
                        kb[(((long)(b * H_ + h)) * T_ + t) * D_ + d] = __float2bfloat16(acc[i][j][r]);
                    else   // Q pre-scaled by C^-0.5 = 1/32 (exact in bf16)
                        qb[(((long)(b * H_ + h)) * T_ + t) * D_ + d] = __float2bfloat16(acc[i][j][r] * 0.03125f);
                }
            }
        }
    }
}

// ---------------- flash v4 (unchanged from round 7) ----------------
__device__ inline void subtile(const bf16x8& qf0, const bf16x8& qf1,
                               f32x4* o, f32x4& l,
                               const short* Ks, const short* Vs, short* myP,
                               int q0, int kbase, int h2, int w, int g, int ln,
                               const bf16x8& ones) {
    f32x4 s[4] = {};
#pragma unroll
    for (int kj = 0; kj < 4; kj++) {
        const int krow = h2 * 64 + kj * 16 + ln;
        const bf16x8 kf0 = *(const bf16x8*)&Ks[krow * 64 + ((0 + g) ^ (krow & 7)) * 8];
        s[kj] = __builtin_amdgcn_mfma_f32_16x16x32_bf16(qf0, kf0, s[kj], 0, 0, 0);
        const bf16x8 kf1 = *(const bf16x8*)&Ks[krow * 64 + ((4 + g) ^ (krow & 7)) * 8];
        s[kj] = __builtin_amdgcn_mfma_f32_16x16x32_bf16(qf1, kf1, s[kj], 0, 0, 0);
    }
    const int rowg = q0 + w * 16 + g * 4;   // + r
    if (kbase == q0) {                      // diagonal sub-tile: causal mask
#pragma unroll
        for (int kj = 0; kj < 4; kj++) {
            const int key = kbase + kj * 16 + ln;
#pragma unroll
            for (int r = 0; r < 4; r++) {
                float p = __expf(s[kj][r]);            // Q pre-scaled: no mul here
                p = (key <= rowg + r) ? p : 0.f;
                const int prow = g * 4 + r;
                const int pc8 = (kj * 2 + (ln >> 3)) ^ (prow & 7);
                myP[prow * 64 + pc8 * 8 + (ln & 7)] = f2bs(p);
            }
        }
    } else {                                // strictly-below-diagonal: unmasked
#pragma unroll
        for (int kj = 0; kj < 4; kj++) {
#pragma unroll
            for (int r = 0; r < 4; r++) {
                const int prow = g * 4 + r;
                const int pc8 = (kj * 2 + (ln >> 3)) ^ (prow & 7);
                myP[prow * 64 + pc8 * 8 + (ln & 7)] = f2bs(__expf(s[kj][r]));
            }
        }
    }
    asm volatile("s_waitcnt lgkmcnt(0)" ::: "memory");   // wave-local P RAW
    const bf16x8 pf0 = *(const bf16x8*)&myP[ln * 64 + ((0 + g) ^ (ln & 7)) * 8];
    const bf16x8 pf1 = *(const bf16x8*)&myP[ln * 64 + ((4 + g) ^ (ln & 7)) * 8];
    l = __builtin_amdgcn_mfma_f32_16x16x32_bf16(ones, pf0, l, 0, 0, 0);
    l = __builtin_amdgcn_mfma_f32_16x16x32_bf16(ones, pf1, l, 0, 0, 0);
#pragma unroll
    for (int nb = 0; nb < 4; nb++) {
        const int drow = nb * 16 + ln;
        const bf16x8 vf0 = *(const bf16x8*)&Vs[drow * 128 + ((h2 * 8 + 0 + g) ^ (drow & 7)) * 8];
        o[nb] = __builtin_amdgcn_mfma_f32_16x16x32_bf16(vf0, pf0, o[nb], 0, 0, 0);
        const bf16x8 vf1 = *(const bf16x8*)&Vs[drow * 128 + ((h2 * 8 + 4 + g) ^ (drow & 7)) * 8];
        o[nb] = __builtin_amdgcn_mfma_f32_16x16x32_bf16(vf1, pf1, o[nb], 0, 0, 0);
    }
}

__global__ __launch_bounds__(256, 4) void flash(const bf16* __restrict__ qb,
                                                const bf16* __restrict__ kb,
                                                const bf16* __restrict__ vbT,
                                                bf16* __restrict__ att) {
    __shared__ __align__(16) short Ks[128 * 64];     // [key][d]  chunk^=key&7
    __shared__ __align__(16) short Vs[64 * 128];     // [d][key]  chunk^=d&7
    __shared__ __align__(16) short Ps[4 * 16 * 64];  // per-wave [qrow][key] swizzled
    const int tid = threadIdx.x, w = tid >> 6, lane = tid & 63;
    const int g = lane >> 4, ln = lane & 15;
    const int lin = blockIdx.x;
    const int bh = lin & 63, p = lin >> 6;
    const int b = bh >> 4, h = bh & 15;
    const int q0A = p * 64, q0B = (31 - p) * 64;

    // Q fragments (A-layout), pre-scaled by 1/32 in gemm0
    const bf16* qpA = qb + ((long)bh * T_ + q0A + w * 16 + ln) * D_;
    const bf16* qpB = qb + ((long)bh * T_ + q0B + w * 16 + ln) * D_;
    const bf16x8 qfA0 = *(const bf16x8*)(qpA + g * 8);
    const bf16x8 qfA1 = *(const bf16x8*)(qpA + 32 + g * 8);
    const bf16x8 qfB0 = *(const bf16x8*)(qpB + g * 8);
    const bf16x8 qfB1 = *(const bf16x8*)(qpB + 32 + g * 8);

    bf16x8 ones;
#pragma unroll
    for (int i = 0; i < 8; i++) ones[i] = 0x3F80;    // bf16 1.0

    f32x4 oA[4] = {}, oB[4] = {};
    f32x4 lA = {}, lB = {};
    short* myP = &Ps[w * 16 * 64];

    const int nstB = (q0B + 64 + 127) >> 7;          // stagings needed (B superset of A)
    for (int s = 0; s < nstB; s++) {
        const int k0 = s * 128;
        bf16x8 kr[4], vr[4];
#pragma unroll
        for (int i = 0; i < 4; i++) {
            const int cc = i * 256 + tid;
            kr[i] = *(const bf16x8*)&kb [((long)bh * T_ + k0 + (cc >> 3)) * D_ + (cc & 7) * 8];
            vr[i] = *(const bf16x8*)&vbT[((long)bh * D_ + (cc >> 4)) * T_ + k0 + (cc & 15) * 8];
        }
        __syncthreads();   // previous tile's reads done
#pragma unroll
        for (int i = 0; i < 4; i++) {
            const int cc = i * 256 + tid;
            const int key = cc >> 3, c8 = cc & 7;
            *(bf16x8*)&Ks[key * 64 + (c8 ^ (key & 7)) * 8] = kr[i];
            const int d = cc >> 4, c16 = cc & 15;
            *(bf16x8*)&Vs[d * 128 + (c16 ^ (d & 7)) * 8] = vr[i];
        }
        __syncthreads();   // staging visible

#pragma unroll
        for (int h2 = 0; h2 < 2; h2++) {
            const int kbase = k0 + h2 * 64;
            if (kbase <= q0A + 63)
                subtile(qfA0, qfA1, oA, lA, Ks, Vs, myP, q0A, kbase, h2, w, g, ln, ones);
            if (kbase <= q0B + 63)
                subtile(qfB0, qfB1, oB, lB, Ks, Vs, myP, q0B, kbase, h2, w, g, ln, ones);
        }
    }

    // ---- epilogue: O^T C-layout row=d local (g*4+r), col=q=ln; divide by l ----
#pragma unroll
    for (int ti = 0; ti < 2; ti++) {
        const f32x4* o = ti ? oB : oA;
        const float invl = 1.f / (ti ? lB[0] : lA[0]);
        const int q = (ti ? q0B : q0A) + w * 16 + ln;
#pragma unroll
        for (int nb = 0; nb < 4; nb++) {
            bf16x4 pk;
#pragma unroll
            for (int r = 0; r < 4; r++) pk[r] = f2bs(o[nb][r] * invl);
            *(bf16x4*)&att[((long)b * T_ + q) * C_ + h * D_ + nb * 16 + g * 4] = pk;
        }
    }
}

// ---------------- launch ----------------
extern "C" void kernel_launch(void* const* d_in, const int* in_sizes, int n_in,
                              void* d_out, int out_size, void* d_ws, size_t ws_size,
                              hipStream_t stream) {
    const float* x     = (const float*)d_in[0];   // [B,T,C] fp32
    const float* Wqkv  = (const float*)d_in[1];   // [C,3C]  fp32
    const float* Wproj = (const float*)d_in[2];   // [C,C]   fp32
    float* out = (float*)d_out;                   // [B,T,C] fp32

    // Liveness-planned workspace (75.5 MB):
    //  att aliases xb (xb dead after gemm0; flash writes att after gemm0)
    char* ws = (char*)d_ws;
    bf16* wqkv_t  = (bf16*)(ws);                 // [3072,1024] bf16  6291456 B
    bf16* wproj_t = (bf16*)(ws + 6291456);       // [1024,1024] bf16  2097152 B
    bf16* qb      = (bf16*)(ws + 8388608);       // [B,H,T,D]   bf16 16777216 B
    bf16* kb      = (bf16*)(ws + 25165824);      // [B,H,T,D]   bf16 16777216 B
    bf16* vbT     = (bf16*)(ws + 41943040);      // [B,H,D,T]   bf16 16777216 B
    bf16* xb      = (bf16*)(ws + 58720256);      // [B,T,C]     bf16 16777216 B
    bf16* att     = xb;                          // alias (after gemm0)
    (void)ws_size; (void)in_sizes; (void)n_in; (void)out_size;

    prep<<<dim3(8192), dim3(256), 0, stream>>>(x, Wqkv, Wproj, xb, wqkv_t, wproj_t);
    gemm_bt<0><<<dim3(NQKV / 128, M_ / 128), dim3(256), 0, stream>>>(
        xb, wqkv_t, (float*)nullptr, qb, kb, vbT, C_, NQKV);
    flash<<<dim3(1024), dim3(256), 0, stream>>>(qb, kb, vbT, att);
    gemm_bt<1><<<dim3(C_ / 128, M_ / 128), dim3(256), 0, stream>>>(
        att, wproj_t, out, (bf16*)nullptr, (bf16*)nullptr, (bf16*)nullptr, C_, C_);
}